// Round 14
// baseline (360.683 us; speedup 1.0000x reference)
//
#include <hip/hip_runtime.h>
#include <hip/hip_bf16.h>

// Problem constants (fixed by reference)
#define BB    2
#define NNODE 4096
#define DD    128
#define KK    32
#define CFX   16

typedef __attribute__((ext_vector_type(8))) short bf16x8;
typedef __attribute__((ext_vector_type(4))) float f32x4;

__device__ __forceinline__ unsigned short f2bf(float f) {
    __hip_bfloat16 h = __float2bfloat16(f);
    return *reinterpret_cast<unsigned short*>(&h);
}
__device__ __forceinline__ unsigned pk2(float lo, float hi) {
    __hip_bfloat162 v = __float22bfloat162_rn(make_float2(lo, hi));
    return *reinterpret_cast<unsigned*>(&v);
}
// Fast silu: v * rcp(1+e^-v) — ~1ulp rcp vs full IEEE divide; output bf16-rounded anyway.
__device__ __forceinline__ float silu_f(float v) {
    float e = __expf(-v);
    return v * __builtin_amdgcn_rcpf(1.f + e);
}
// Exact dist (reference mul-then-add order, no FMA contraction) — bit-identical everywhere.
__device__ __forceinline__ float dist3c(float xi0, float xi1, float xi2,
                                        const float* __restrict__ xb, int j) {
    float d0 = __fsub_rn(xi0, xb[3 * j]);
    float d1 = __fsub_rn(xi1, xb[3 * j + 1]);
    float d2 = __fsub_rn(xi2, xb[3 * j + 2]);
    return __fadd_rn(__fadd_rn(__fmul_rn(d0, d0), __fmul_rn(d1, d1)), __fmul_rn(d2, d2));
}

// ---------------------------------------------------------------- prep: pack weights into MFMA fragment layout
__global__ void prep_kernel(const float* __restrict__ We1, const float* __restrict__ We2,
                            const float* __restrict__ Wn1, const float* __restrict__ Wn2,
                            unsigned short* __restrict__ W1pack, unsigned short* __restrict__ W2p2,
                            unsigned short* __restrict__ Wn1p, unsigned short* __restrict__ Wn2p) {
    int tid = blockIdx.x * 256 + threadIdx.x;
    int stride = gridDim.x * 256;
    for (int p = tid; p < 9 * 36 * 64 * 8; p += stride) {
        int i = p & 7, lane = (p >> 3) & 63, rest = p >> 9;
        int nb = rest % 36, ks = rest / 36;
        int n = nb * 16 + (lane & 15);
        int k = ks * 32 + 8 * (lane >> 4) + i;
        W1pack[p] = (k < 257 && n < 514) ? f2bf(We1[k * 514 + n]) : (unsigned short)0;
    }
    for (int p = tid; p < 4 * 5 * 64 * 8; p += stride) {
        int i = p & 7, lane = (p >> 3) & 63, rest = p >> 9;
        int ks2 = rest % 5, wn = rest / 5;
        int g = lane >> 4, f = lane & 15;
        int nloc = ks2 * 32 + 16 * (i >> 2) + 4 * g + (i & 3);
        int ng = wn * 144 + nloc;
        W2p2[p] = (nloc < 144 && ng < 514) ? f2bf(We2[ng * 16 + f]) : (unsigned short)0;
    }
    for (int p = tid; p < 5 * 16 * 64 * 8; p += stride) {
        int i = p & 7, lane = (p >> 3) & 63, rest = p >> 9;
        int nb = rest % 16, ks = rest / 16;
        int u = nb * 16 + (lane & 15);
        int k = ks * 32 + 8 * (lane >> 4) + i;
        Wn1p[p] = (k < 144) ? f2bf(Wn1[k * 256 + u]) : (unsigned short)0;
    }
    for (int p = tid; p < 8 * 8 * 64 * 8; p += stride) {
        int i = p & 7, lane = (p >> 3) & 63, rest = p >> 9;
        int nb = rest % 8, ks = rest / 8;
        int d = nb * 16 + (lane & 15);
        int k = ks * 32 + 8 * (lane >> 4) + i;
        Wn2p[p] = f2bf(Wn2[k * 128 + d]);
    }
}

// ---------------------------------------------------------------- fused kNN + edge MLP (MFMA) + coors
// Phase 0: kNN for the block's 2 nodes (R13-v4 radix select, 2 queries sharing x loads).
//   Scratch aliased onto m_s4/m_sF (dead in this phase); results stay in LDS (j_s, dist_e,
//   rel_s) — no idx/relk/distk globals. One block's knn overlaps the other's GEMM (m114).
// Phase 1+: EXACT R9/R13 edge structure (proven 229us; (256,2) = only non-spilling tier).
#define EQCAP 36
#define CANDCAP 1024
__global__ __launch_bounds__(256, 2) void edge_kernel(
    const float* __restrict__ h, const float* __restrict__ x, const int* __restrict__ mask,
    const float* __restrict__ be1, const float* __restrict__ be2,
    const float* __restrict__ Wc1, const float* __restrict__ bc1,
    const float* __restrict__ Wc2, const float* __restrict__ bc2,
    const unsigned short* __restrict__ W1pack, const unsigned short* __restrict__ W2p2,
    float* __restrict__ m_i_out, float* __restrict__ coors_out)
{
    __shared__ unsigned short E2[64][168];
    __shared__ unsigned short hi_s[2][136];
    __shared__ float be1s[576];
    __shared__ int   j_s[64];
    __shared__ float cw_s[64];
    __shared__ float m_s4[4 * 64 * 16];     // GEMM phase; knn phase aliases hist+cand here
    __shared__ float m_sF[64 * 17];         // GEMM phase; knn phase aliases scalars here
    __shared__ float dist_e[64];
    __shared__ float rel_s[64][3];

    const int t = threadIdx.x;
    const int gn0 = blockIdx.x * 2;
    const int b = gn0 >> 12;
    const int wn = t >> 6, lane = t & 63;
    const int l15 = lane & 15, g = lane >> 4;
    const int ln = lane, wv = wn;

    // ---- early staging (independent of knn): h_i, be1
    {
        int n = t >> 7, c = t & 127;
        hi_s[n][c] = f2bf(h[(size_t)(gn0 + n) * DD + c]);
    }
    for (int i2 = t; i2 < 576; i2 += 256) be1s[i2] = (i2 < 514) ? be1[i2] : 0.f;

    // ================= Phase 0: kNN for nodes gn0, gn0+1 =================
    {
        unsigned* histA = (unsigned*)m_s4;            // [2][4][256] = 8 KB
        uint2*    candA = (uint2*)(m_s4 + 2048);      // 1024 pairs = 8 KB
        unsigned* wsum  = (unsigned*)m_sF;            // 4
        unsigned* sel   = wsum + 4;                   // 2
        unsigned* shAB  = sel + 2;                    // 2
        int* out_jA     = (int*)(shAB + 2);           // 32
        int* eqbufA     = out_jA + 32;                // 36

        const float* xb = x + (size_t)b * NNODE * 3;
        const int i0 = gn0 & 4095;
        float xi[2][3];
        #pragma unroll
        for (int q = 0; q < 2; ++q) {
            xi[q][0] = xb[3 * (i0 + q)];
            xi[q][1] = xb[3 * (i0 + q) + 1];
            xi[q][2] = xb[3 * (i0 + q) + 2];
        }
        for (int z = t; z < 2048; z += 256) histA[z] = 0;
        __syncthreads();

        // pass 1: shared x loads, dists for both queries into regs + round-0 hists
        unsigned ub[2][16];
        #pragma unroll
        for (int s = 0; s < 16; ++s) {
            int j = t + 256 * s;
            float xj0 = xb[3 * j], xj1 = xb[3 * j + 1], xj2 = xb[3 * j + 2];
            #pragma unroll
            for (int q = 0; q < 2; ++q) {
                float d0 = __fsub_rn(xi[q][0], xj0);
                float d1 = __fsub_rn(xi[q][1], xj1);
                float d2 = __fsub_rn(xi[q][2], xj2);
                float d = __fadd_rn(__fadd_rn(__fmul_rn(d0, d0), __fmul_rn(d1, d1)), __fmul_rn(d2, d2));
                ub[q][s] = __float_as_uint(d);
                atomicAdd(&histA[(q * 4 + wv) * 256 + (ub[q][s] >> 24)], 1u);
            }
        }
        __syncthreads();

        #pragma unroll
        for (int q = 0; q < 2; ++q) {
            int kk = KK;
            // select round 0 (from prebuilt hist[q])
            {
                unsigned hv = histA[(q * 4 + 0) * 256 + t] + histA[(q * 4 + 1) * 256 + t]
                            + histA[(q * 4 + 2) * 256 + t] + histA[(q * 4 + 3) * 256 + t];
                unsigned v = hv;
                #pragma unroll
                for (int off = 1; off < 64; off <<= 1) {
                    unsigned o = __shfl_up(v, off, 64);
                    if (ln >= off) v += o;
                }
                if (ln == 63) wsum[wv] = v;
                __syncthreads();
                unsigned add = 0;
                #pragma unroll
                for (int w = 0; w < 4; ++w) add += (w < wv) ? wsum[w] : 0u;
                unsigned incl = v + add, excl = incl - hv;
                if ((unsigned)kk > excl && (unsigned)kk <= incl) { sel[0] = (unsigned)t; sel[1] = (unsigned)kk - excl; }
                __syncthreads();
            }
            unsigned prefix = sel[0];
            kk = (int)sel[1];
            __syncthreads();

            // pass 2 (regs): packed count, prefix-scan, deterministic write
            unsigned pc = 0;
            #pragma unroll
            for (int s = 0; s < 16; ++s) {
                unsigned tb = ub[q][s] >> 24;
                pc += (tb < prefix) ? 0x10000u : (tb == prefix ? 1u : 0u);
            }
            {
                unsigned v = pc;
                #pragma unroll
                for (int off = 1; off < 64; off <<= 1) {
                    unsigned o = __shfl_up(v, off, 64);
                    if (ln >= off) v += o;
                }
                if (ln == 63) wsum[wv] = v;
                __syncthreads();
                unsigned add = 0;
                #pragma unroll
                for (int w = 0; w < 4; ++w) add += (w < wv) ? wsum[w] : 0u;
                unsigned incl = v + add, excl = incl - pc;
                if (t == 255) { shAB[0] = incl >> 16; shAB[1] = incl & 0xFFFFu; }
                __syncthreads();
                unsigned wl = excl >> 16, wc = excl & 0xFFFFu;
                #pragma unroll
                for (int s = 0; s < 16; ++s) {
                    unsigned u = ub[q][s];
                    unsigned tb = u >> 24;
                    int j = t + 256 * s;
                    if (tb < prefix) { out_jA[wl++] = j; }
                    else if (tb == prefix) { if (wc < CANDCAP) candA[wc] = make_uint2(u, (unsigned)j); ++wc; }
                }
            }
            __syncthreads();
            const unsigned totL0 = shAB[0], totC = shAB[1];
            const bool fullscan = (totC > CANDCAP);

            // rounds 1..3 over candidate pairs (hist[0] region; q1's round-0 half untouched)
            for (int r = 1; r < 4; ++r) {
                const int sh = 24 - 8 * r;
                #pragma unroll
                for (int q2 = 0; q2 < 4; ++q2) histA[q2 * 256 + t] = 0;
                __syncthreads();
                if (!fullscan) {
                    for (int ii = t; ii < (int)totC; ii += 256) {
                        unsigned u = candA[ii].x;
                        if ((u >> (sh + 8)) == prefix) atomicAdd(&histA[wv * 256 + ((u >> sh) & 255)], 1u);
                    }
                } else {
                    #pragma unroll
                    for (int s = 0; s < 16; ++s) {
                        unsigned u = ub[q][s];
                        if ((u >> (sh + 8)) == prefix) atomicAdd(&histA[wv * 256 + ((u >> sh) & 255)], 1u);
                    }
                }
                __syncthreads();
                unsigned hv = histA[t] + histA[256 + t] + histA[512 + t] + histA[768 + t];
                unsigned v = hv;
                #pragma unroll
                for (int off = 1; off < 64; off <<= 1) {
                    unsigned o = __shfl_up(v, off, 64);
                    if (ln >= off) v += o;
                }
                if (ln == 63) wsum[wv] = v;
                __syncthreads();
                unsigned add = 0;
                #pragma unroll
                for (int w = 0; w < 4; ++w) add += (w < wv) ? wsum[w] : 0u;
                unsigned incl = v + add, excl = incl - hv;
                if ((unsigned)kk > excl && (unsigned)kk <= incl) { sel[0] = (unsigned)t; sel[1] = (unsigned)kk - excl; }
                __syncthreads();
                prefix = (prefix << 8) | sel[0];
                kk = (int)sel[1];
                __syncthreads();
            }
            const unsigned T = prefix;

            // final collection
            int totL;
            if (!fullscan) {
                unsigned pc2 = 0;
                for (int ii = t; ii < (int)totC; ii += 256) {
                    unsigned u = candA[ii].x;
                    pc2 += (u < T) ? 0x10000u : (u == T ? 1u : 0u);
                }
                unsigned v = pc2;
                #pragma unroll
                for (int off = 1; off < 64; off <<= 1) {
                    unsigned o = __shfl_up(v, off, 64);
                    if (ln >= off) v += o;
                }
                if (ln == 63) wsum[wv] = v;
                __syncthreads();
                unsigned add = 0;
                #pragma unroll
                for (int w = 0; w < 4; ++w) add += (w < wv) ? wsum[w] : 0u;
                unsigned incl = v + add, excl = incl - pc2;
                if (t == 255) { shAB[0] = incl >> 16; shAB[1] = incl & 0xFFFFu; }
                __syncthreads();
                unsigned w2 = totL0 + (excl >> 16), we = excl & 0xFFFFu;
                for (int ii = t; ii < (int)totC; ii += 256) {
                    unsigned u = candA[ii].x;
                    int j = (int)candA[ii].y;
                    if (u < T) { out_jA[w2++] = j; }
                    else if (u == T) { if (we < EQCAP) eqbufA[we] = j; ++we; }
                }
                __syncthreads();
                totL = (int)(totL0 + shAB[0]);
                const unsigned totE = shAB[1];
                if (t == 0) {
                    int need = KK - totL;
                    if (totE <= EQCAP) {
                        for (int a = 1; a < (int)totE; ++a) {
                            int key = eqbufA[a], c = a - 1;
                            while (c >= 0 && eqbufA[c] > key) { eqbufA[c + 1] = eqbufA[c]; --c; }
                            eqbufA[c + 1] = key;
                        }
                        for (int q3 = 0; q3 < need; ++q3) out_jA[totL + q3] = eqbufA[q3];
                    } else {
                        int taken = 0;
                        for (int j = 0; j < NNODE && taken < need; ++j)
                            if (__float_as_uint(dist3c(xi[q][0], xi[q][1], xi[q][2], xb, j)) == T)
                                out_jA[totL + taken++] = j;
                    }
                }
            } else {
                unsigned pc2 = 0;
                #pragma unroll
                for (int s = 0; s < 16; ++s) {
                    unsigned u = ub[q][s];
                    pc2 += (u < T) ? 0x10000u : (u == T ? 1u : 0u);
                }
                unsigned v = pc2;
                #pragma unroll
                for (int off = 1; off < 64; off <<= 1) {
                    unsigned o = __shfl_up(v, off, 64);
                    if (ln >= off) v += o;
                }
                if (ln == 63) wsum[wv] = v;
                __syncthreads();
                unsigned add = 0;
                #pragma unroll
                for (int w = 0; w < 4; ++w) add += (w < wv) ? wsum[w] : 0u;
                unsigned incl = v + add, excl = incl - pc2;
                if (t == 255) { shAB[0] = incl >> 16; shAB[1] = incl & 0xFFFFu; }
                __syncthreads();
                unsigned w2 = excl >> 16, we = excl & 0xFFFFu;
                #pragma unroll
                for (int s = 0; s < 16; ++s) {
                    unsigned u = ub[q][s];
                    int j = t + 256 * s;
                    if (u < T) { out_jA[w2++] = j; }
                    else if (u == T) { if (we < EQCAP) eqbufA[we] = j; ++we; }
                }
                __syncthreads();
                totL = (int)shAB[0];
                const unsigned totE = shAB[1];
                if (t == 0) {
                    int need = KK - totL;
                    if (totE <= EQCAP) {
                        for (int a = 1; a < (int)totE; ++a) {
                            int key = eqbufA[a], c = a - 1;
                            while (c >= 0 && eqbufA[c] > key) { eqbufA[c + 1] = eqbufA[c]; --c; }
                            eqbufA[c + 1] = key;
                        }
                        for (int q3 = 0; q3 < need; ++q3) out_jA[totL + q3] = eqbufA[q3];
                    } else {
                        int taken = 0;
                        for (int j = 0; j < NNODE && taken < need; ++j)
                            if (__float_as_uint(dist3c(xi[q][0], xi[q][1], xi[q][2], xb, j)) == T)
                                out_jA[totL + taken++] = j;
                    }
                }
            }
            __syncthreads();

            if (t < KK) {
                int j = out_jA[t];
                int e = q * 32 + t;
                j_s[e] = j;
                float r0 = __fsub_rn(xi[q][0], xb[3 * j]);
                float r1 = __fsub_rn(xi[q][1], xb[3 * j + 1]);
                float r2 = __fsub_rn(xi[q][2], xb[3 * j + 2]);
                rel_s[e][0] = r0;
                rel_s[e][1] = r1;
                rel_s[e][2] = r2;
                dist_e[e] = __fadd_rn(__fadd_rn(__fmul_rn(r0, r0), __fmul_rn(r1, r1)), __fmul_rn(r2, r2));
            }
            __syncthreads();
        }
    }
    // ================= Phase 1: edge staging (R13 structure) =================
    if (t < 64) {
        ushort2* p = (ushort2*)&E2[t][128];
        p[0] = make_ushort2(f2bf(dist_e[t]), 0);
        #pragma unroll
        for (int z = 1; z < 20; ++z) p[z] = make_ushort2(0, 0);
    }
    __syncthreads();
    for (int q = t; q < 64 * 32; q += 256) {
        int e = q >> 5, d4 = q & 31;
        int j = j_s[e];
        float4 v = *(const float4*)(h + ((size_t)b * NNODE + j) * DD + d4 * 4);
        *(uint2*)&E2[e][d4 * 4] = make_uint2(pk2(v.x, v.y), pk2(v.z, v.w));
    }
    __syncthreads();

    const bf16x8* W1v = (const bf16x8*)W1pack;
    const bf16x8* W2v = (const bf16x8*)W2p2;
    int erow[4];
    #pragma unroll
    for (int et = 0; et < 4; ++et) erow[et] = et * 16 + l15;

    f32x4 acc2[4];
    #pragma unroll
    for (int et = 0; et < 4; ++et)
        #pragma unroll
        for (int r = 0; r < 4; ++r) acc2[et][r] = 0.f;

    #pragma unroll
    for (int c = 0; c < 2; ++c) {
        f32x4 acc[4][4];
        #pragma unroll
        for (int nb = 0; nb < 4; ++nb)
            #pragma unroll
            for (int et = 0; et < 4; ++et)
                #pragma unroll
                for (int r = 0; r < 4; ++r) acc[nb][et][r] = 0.f;
        #pragma unroll
        for (int ks = 0; ks < 9; ++ks) {
            const bf16x8* wp = W1v + ((size_t)(ks * 36 + wn * 9 + c * 4)) * 64 + lane;
            bf16x8 afr[4];
            #pragma unroll
            for (int nb = 0; nb < 4; ++nb) afr[nb] = wp[nb * 64];
            bf16x8 bfr[4];
            if (ks < 4) {
                bf16x8 b0 = *(const bf16x8*)&hi_s[0][ks * 32 + 8 * g];
                bf16x8 b1 = *(const bf16x8*)&hi_s[1][ks * 32 + 8 * g];
                bfr[0] = b0; bfr[1] = b0; bfr[2] = b1; bfr[3] = b1;
            } else {
                #pragma unroll
                for (int et = 0; et < 4; ++et)
                    bfr[et] = *(const bf16x8*)&E2[erow[et]][(ks - 4) * 32 + 8 * g];
            }
            #pragma unroll
            for (int nb = 0; nb < 4; ++nb)
                #pragma unroll
                for (int et = 0; et < 4; ++et)
                    acc[nb][et] = __builtin_amdgcn_mfma_f32_16x16x32_bf16(afr[nb], bfr[et], acc[nb][et], 0, 0, 0);
        }
        #pragma unroll
        for (int nb = 0; nb < 4; ++nb) {
            f32x4 bv = *(const f32x4*)&be1s[wn * 144 + (c * 4 + nb) * 16 + 4 * g];
            #pragma unroll
            for (int et = 0; et < 4; ++et)
                #pragma unroll
                for (int r = 0; r < 4; ++r)
                    acc[nb][et][r] = silu_f(acc[nb][et][r] + bv[r]);
        }
        #pragma unroll
        for (int qq = 0; qq < 2; ++qq) {
            int ks2 = 2 * c + qq;
            bf16x8 a2 = W2v[(size_t)(wn * 5 + ks2) * 64 + lane];
            #pragma unroll
            for (int et = 0; et < 4; ++et) {
                union { unsigned u[4]; bf16x8 v; } cv;
                cv.u[0] = pk2(acc[2 * qq][et][0], acc[2 * qq][et][1]);
                cv.u[1] = pk2(acc[2 * qq][et][2], acc[2 * qq][et][3]);
                cv.u[2] = pk2(acc[2 * qq + 1][et][0], acc[2 * qq + 1][et][1]);
                cv.u[3] = pk2(acc[2 * qq + 1][et][2], acc[2 * qq + 1][et][3]);
                acc2[et] = __builtin_amdgcn_mfma_f32_16x16x32_bf16(a2, cv.v, acc2[et], 0, 0, 0);
            }
        }
    }
    {
        f32x4 acc8[4];
        #pragma unroll
        for (int et = 0; et < 4; ++et)
            #pragma unroll
            for (int r = 0; r < 4; ++r) acc8[et][r] = 0.f;
        #pragma unroll
        for (int ks = 0; ks < 9; ++ks) {
            bf16x8 af = W1v[((size_t)(ks * 36 + wn * 9 + 8)) * 64 + lane];
            bf16x8 bfr[4];
            if (ks < 4) {
                bf16x8 b0 = *(const bf16x8*)&hi_s[0][ks * 32 + 8 * g];
                bf16x8 b1 = *(const bf16x8*)&hi_s[1][ks * 32 + 8 * g];
                bfr[0] = b0; bfr[1] = b0; bfr[2] = b1; bfr[3] = b1;
            } else {
                #pragma unroll
                for (int et = 0; et < 4; ++et)
                    bfr[et] = *(const bf16x8*)&E2[erow[et]][(ks - 4) * 32 + 8 * g];
            }
            #pragma unroll
            for (int et = 0; et < 4; ++et)
                acc8[et] = __builtin_amdgcn_mfma_f32_16x16x32_bf16(af, bfr[et], acc8[et], 0, 0, 0);
        }
        f32x4 bv = *(const f32x4*)&be1s[wn * 144 + 128 + 4 * g];
        #pragma unroll
        for (int et = 0; et < 4; ++et)
            #pragma unroll
            for (int r = 0; r < 4; ++r)
                acc8[et][r] = silu_f(acc8[et][r] + bv[r]);
        bf16x8 a2 = W2v[(size_t)(wn * 5 + 4) * 64 + lane];
        #pragma unroll
        for (int et = 0; et < 4; ++et) {
            union { unsigned u[4]; bf16x8 v; } cv;
            cv.u[0] = pk2(acc8[et][0], acc8[et][1]);
            cv.u[1] = pk2(acc8[et][2], acc8[et][3]);
            cv.u[2] = 0; cv.u[3] = 0;
            acc2[et] = __builtin_amdgcn_mfma_f32_16x16x32_bf16(a2, cv.v, acc2[et], 0, 0, 0);
        }
    }
    #pragma unroll
    for (int et = 0; et < 4; ++et)
        *(f32x4*)&m_s4[((wn * 64) + erow[et]) * 16 + 4 * g] = acc2[et];
    __syncthreads();

    #pragma unroll
    for (int i2 = t; i2 < 64 * 16; i2 += 256) {
        int e = i2 >> 4, f = i2 & 15;
        float s = m_s4[e * 16 + f] + m_s4[(64 + e) * 16 + f]
                + m_s4[(128 + e) * 16 + f] + m_s4[(192 + e) * 16 + f];
        m_sF[e * 17 + f] = silu_f(s + be2[f]);
    }
    __syncthreads();

    {
        const int ee = t >> 2, q4 = t & 3;
        const int u0 = q4 * 16;
        float mm[16];
        #pragma unroll
        for (int f = 0; f < 16; ++f) mm[f] = m_sF[ee * 17 + f];
        float h2[16];
        {
            const float4* bp = (const float4*)(bc1 + u0);
            float4 b0 = bp[0], b1 = bp[1], b2v = bp[2], b3 = bp[3];
            h2[0]=b0.x; h2[1]=b0.y; h2[2]=b0.z; h2[3]=b0.w;
            h2[4]=b1.x; h2[5]=b1.y; h2[6]=b1.z; h2[7]=b1.w;
            h2[8]=b2v.x; h2[9]=b2v.y; h2[10]=b2v.z; h2[11]=b2v.w;
            h2[12]=b3.x; h2[13]=b3.y; h2[14]=b3.z; h2[15]=b3.w;
        }
        #pragma unroll
        for (int f = 0; f < 16; ++f) {
            const float4* wp = (const float4*)(Wc1 + (size_t)f * 64 + u0);
            float4 w0 = wp[0], w1 = wp[1], w2 = wp[2], w3 = wp[3];
            float v = mm[f];
            h2[0]  = fmaf(v, w0.x, h2[0]);  h2[1]  = fmaf(v, w0.y, h2[1]);
            h2[2]  = fmaf(v, w0.z, h2[2]);  h2[3]  = fmaf(v, w0.w, h2[3]);
            h2[4]  = fmaf(v, w1.x, h2[4]);  h2[5]  = fmaf(v, w1.y, h2[5]);
            h2[6]  = fmaf(v, w1.z, h2[6]);  h2[7]  = fmaf(v, w1.w, h2[7]);
            h2[8]  = fmaf(v, w2.x, h2[8]);  h2[9]  = fmaf(v, w2.y, h2[9]);
            h2[10] = fmaf(v, w2.z, h2[10]); h2[11] = fmaf(v, w2.w, h2[11]);
            h2[12] = fmaf(v, w3.x, h2[12]); h2[13] = fmaf(v, w3.y, h2[13]);
            h2[14] = fmaf(v, w3.z, h2[14]); h2[15] = fmaf(v, w3.w, h2[15]);
        }
        float cw = 0.f;
        const float4* cp = (const float4*)(Wc2 + u0);
        float4 c0 = cp[0], c1 = cp[1], c2 = cp[2], c3 = cp[3];
        const float wv2[16] = {c0.x,c0.y,c0.z,c0.w, c1.x,c1.y,c1.z,c1.w,
                               c2.x,c2.y,c2.z,c2.w, c3.x,c3.y,c3.z,c3.w};
        #pragma unroll
        for (int r = 0; r < 16; ++r) cw = fmaf(silu_f(h2[r]), wv2[r], cw);
        cw += __shfl_xor(cw, 1, 64);
        cw += __shfl_xor(cw, 2, 64);
        if (q4 == 0) {
            cw += bc2[0];
            int gnode = gn0 + (ee >> 5);
            int mi = mask[gnode];
            int mj = mask[b * NNODE + j_s[ee]];
            cw_s[ee] = (mi != 0 && mj != 0) ? cw : 0.f;
        }
    }
    __syncthreads();

    if (t < 32) {
        int n = t >> 4, f = t & 15;
        float s = 0.f;
        #pragma unroll
        for (int k2 = 0; k2 < 32; ++k2) s += m_sF[(n * 32 + k2) * 17 + f];
        m_i_out[(size_t)(gn0 + n) * CFX + f] = s;
    } else if (t < 38) {
        int r = t - 32;
        int n = r / 3, c = r - n * 3;
        float s = 0.f;
        #pragma unroll
        for (int k2 = 0; k2 < 32; ++k2) s = fmaf(cw_s[n * 32 + k2], rel_s[n * 32 + k2][c], s);
        coors_out[(size_t)(gn0 + n) * 3 + c] = s + x[(size_t)(gn0 + n) * 3 + c];
    }
}

// ---------------------------------------------------------------- node MLP via MFMA (R11 exact — proven)
__global__ __launch_bounds__(256) void node_kernel(
    const float* __restrict__ h, const float* __restrict__ m_i,
    const unsigned short* __restrict__ Wn1p, const float* __restrict__ bn1,
    const unsigned short* __restrict__ Wn2p, const float* __restrict__ bn2,
    float* __restrict__ node_out)
{
    __shared__ unsigned short nin[32][168];
    __shared__ unsigned short hid[32][264];

    const int t = threadIdx.x;
    const int gn0 = blockIdx.x * 32;
    const int wn = t >> 6, lane = t & 63;
    const int l15 = lane & 15, g = lane >> 4;

    for (int q = t; q < 32 * 32; q += 256) {
        int node = q >> 5, c4 = q & 31;
        float4 v = *(const float4*)(h + (size_t)(gn0 + node) * DD + c4 * 4);
        *(uint2*)&nin[node][c4 * 4] = make_uint2(pk2(v.x, v.y), pk2(v.z, v.w));
    }
    if (t < 128) {
        int node = t >> 2, c4 = t & 3;
        float4 v = *(const float4*)(m_i + (size_t)(gn0 + node) * CFX + c4 * 4);
        *(uint2*)&nin[node][128 + c4 * 4] = make_uint2(pk2(v.x, v.y), pk2(v.z, v.w));
    } else if (t < 224) {
        int r = t - 128;
        int node = r / 3, cc = (r - node * 3) * 8;
        *(uint4*)&nin[node][144 + cc] = make_uint4(0, 0, 0, 0);
    }
    __syncthreads();

    const bf16x8* A1 = (const bf16x8*)Wn1p;
    f32x4 acc[4][2];
    #pragma unroll
    for (int nb = 0; nb < 4; ++nb)
        #pragma unroll
        for (int et = 0; et < 2; ++et)
            #pragma unroll
            for (int r = 0; r < 4; ++r) acc[nb][et][r] = 0.f;
    #pragma unroll
    for (int ks = 0; ks < 5; ++ks) {
        const bf16x8* wp = A1 + ((size_t)(ks * 16 + wn * 4)) * 64 + lane;
        bf16x8 afr[4];
        #pragma unroll
        for (int nb = 0; nb < 4; ++nb) afr[nb] = wp[nb * 64];
        bf16x8 b0 = *(const bf16x8*)&nin[l15][ks * 32 + 8 * g];
        bf16x8 b1 = *(const bf16x8*)&nin[16 + l15][ks * 32 + 8 * g];
        #pragma unroll
        for (int nb = 0; nb < 4; ++nb) {
            acc[nb][0] = __builtin_amdgcn_mfma_f32_16x16x32_bf16(afr[nb], b0, acc[nb][0], 0, 0, 0);
            acc[nb][1] = __builtin_amdgcn_mfma_f32_16x16x32_bf16(afr[nb], b1, acc[nb][1], 0, 0, 0);
        }
    }
    #pragma unroll
    for (int nb = 0; nb < 4; ++nb) {
        int u0 = (wn * 4 + nb) * 16 + 4 * g;
        f32x4 bv = *(const f32x4*)&bn1[u0];
        #pragma unroll
        for (int et = 0; et < 2; ++et) {
            float s0 = silu_f(acc[nb][et][0] + bv[0]);
            float s1 = silu_f(acc[nb][et][1] + bv[1]);
            float s2 = silu_f(acc[nb][et][2] + bv[2]);
            float s3 = silu_f(acc[nb][et][3] + bv[3]);
            *(uint2*)&hid[et * 16 + l15][u0] = make_uint2(pk2(s0, s1), pk2(s2, s3));
        }
    }
    __syncthreads();

    const bf16x8* A2 = (const bf16x8*)Wn2p;
    f32x4 acc2[2][2];
    #pragma unroll
    for (int nb = 0; nb < 2; ++nb)
        #pragma unroll
        for (int et = 0; et < 2; ++et)
            #pragma unroll
            for (int r = 0; r < 4; ++r) acc2[nb][et][r] = 0.f;
    #pragma unroll
    for (int ks = 0; ks < 8; ++ks) {
        const bf16x8* wp = A2 + ((size_t)(ks * 8 + wn * 2)) * 64 + lane;
        bf16x8 a0 = wp[0], a1 = wp[64];
        bf16x8 b0 = *(const bf16x8*)&hid[l15][ks * 32 + 8 * g];
        bf16x8 b1 = *(const bf16x8*)&hid[16 + l15][ks * 32 + 8 * g];
        acc2[0][0] = __builtin_amdgcn_mfma_f32_16x16x32_bf16(a0, b0, acc2[0][0], 0, 0, 0);
        acc2[0][1] = __builtin_amdgcn_mfma_f32_16x16x32_bf16(a0, b1, acc2[0][1], 0, 0, 0);
        acc2[1][0] = __builtin_amdgcn_mfma_f32_16x16x32_bf16(a1, b0, acc2[1][0], 0, 0, 0);
        acc2[1][1] = __builtin_amdgcn_mfma_f32_16x16x32_bf16(a1, b1, acc2[1][1], 0, 0, 0);
    }
    #pragma unroll
    for (int nb = 0; nb < 2; ++nb) {
        int d0 = (wn * 2 + nb) * 16 + 4 * g;
        f32x4 bv = *(const f32x4*)&bn2[d0];
        #pragma unroll
        for (int et = 0; et < 2; ++et) {
            int gnode = gn0 + et * 16 + l15;
            float4 hv = *(const float4*)(h + (size_t)gnode * DD + d0);
            float4 o;
            o.x = acc2[nb][et][0] + bv[0] + hv.x;
            o.y = acc2[nb][et][1] + bv[1] + hv.y;
            o.z = acc2[nb][et][2] + bv[2] + hv.z;
            o.w = acc2[nb][et][3] + bv[3] + hv.w;
            *(float4*)(node_out + (size_t)gnode * DD + d0) = o;
        }
    }
}

// ---------------------------------------------------------------- launch
extern "C" void kernel_launch(void* const* d_in, const int* in_sizes, int n_in,
                              void* d_out, int out_size, void* d_ws, size_t ws_size,
                              hipStream_t stream) {
    const float* h   = (const float*)d_in[0];
    const float* x   = (const float*)d_in[1];
    const int*   mask= (const int*)d_in[2];
    const float* We1 = (const float*)d_in[3];
    const float* be1 = (const float*)d_in[4];
    const float* We2 = (const float*)d_in[5];
    const float* be2 = (const float*)d_in[6];
    const float* Wc1 = (const float*)d_in[7];
    const float* bc1 = (const float*)d_in[8];
    const float* Wc2 = (const float*)d_in[9];
    const float* bc2 = (const float*)d_in[10];
    const float* Wn1 = (const float*)d_in[11];
    const float* bn1 = (const float*)d_in[12];
    const float* Wn2 = (const float*)d_in[13];
    const float* bn2 = (const float*)d_in[14];

    float* node_out  = (float*)d_out;
    float* coors_out = node_out + (size_t)BB * NNODE * DD;

    char* ws = (char*)d_ws;
    float* m_i    = (float*)ws;          ws += (size_t)BB * NNODE * CFX * 4;
    unsigned short* W1pack = (unsigned short*)ws;  ws += (size_t)9 * 36 * 64 * 8 * 2;
    unsigned short* W2p2   = (unsigned short*)ws;  ws += (size_t)4 * 5 * 64 * 8 * 2;
    unsigned short* Wn1p   = (unsigned short*)ws;  ws += (size_t)5 * 16 * 64 * 8 * 2;
    unsigned short* Wn2p   = (unsigned short*)ws;  ws += (size_t)8 * 8 * 64 * 8 * 2;

    prep_kernel<<<256, 256, 0, stream>>>(We1, We2, Wn1, Wn2, W1pack, W2p2, Wn1p, Wn2p);
    edge_kernel<<<BB * NNODE / 2, 256, 0, stream>>>(h, x, mask, be1, be2, Wc1, bc1, Wc2, bc2,
                                                    W1pack, W2p2, m_i, coors_out);
    node_kernel<<<BB * NNODE / 32, 256, 0, stream>>>(h, m_i, Wn1p, bn1, Wn2p, bn2, node_out);
}

// Round 15
// 328.333 us; speedup vs baseline: 1.0985x; 1.0985x over previous
//
#include <hip/hip_runtime.h>
#include <hip/hip_bf16.h>

// Problem constants (fixed by reference)
#define BB    2
#define NNODE 4096
#define DD    128
#define KK    32
#define CFX   16

typedef __attribute__((ext_vector_type(8))) short bf16x8;
typedef __attribute__((ext_vector_type(4))) float f32x4;

__device__ __forceinline__ unsigned short f2bf(float f) {
    __hip_bfloat16 h = __float2bfloat16(f);
    return *reinterpret_cast<unsigned short*>(&h);
}
__device__ __forceinline__ unsigned pk2(float lo, float hi) {
    __hip_bfloat162 v = __float22bfloat162_rn(make_float2(lo, hi));
    return *reinterpret_cast<unsigned*>(&v);
}
// Fast silu: v * rcp(1+e^-v) — ~1ulp rcp vs full IEEE divide; output bf16-rounded anyway.
__device__ __forceinline__ float silu_f(float v) {
    float e = __expf(-v);
    return v * __builtin_amdgcn_rcpf(1.f + e);
}
// Exact dist (matches reference mul-then-add, no FMA contraction) — bit-identical everywhere.
__device__ __forceinline__ float dist3(float xi0, float xi1, float xi2,
                                       const float* __restrict__ xb, int j) {
    float d0 = __fsub_rn(xi0, xb[3 * j]);
    float d1 = __fsub_rn(xi1, xb[3 * j + 1]);
    float d2 = __fsub_rn(xi2, xb[3 * j + 2]);
    return __fadd_rn(__fadd_rn(__fmul_rn(d0, d0), __fmul_rn(d1, d1)), __fmul_rn(d2, d2));
}

// ---------------------------------------------------------------- prep: pack weights into MFMA fragment layout
// W1pack[ks 0..8][nbg 0..35][lane][i]: n = nbg*16+(lane&15); k = ks*32+8*(lane>>4)+i
// W2p2[wn 0..3][ks2 0..4][lane][i]:  f = lane&15; g=lane>>4; nloc = ks2*32+16*(i>>2)+4*g+(i&3); ng = wn*144+nloc
// Wn1p[ks 0..4][nb 0..15][lane][i]:  u = nb*16+(lane&15); k = ks*32+8*(lane>>4)+i; val = (k<144)?Wn1[k][u]:0
// Wn2p[ks 0..7][nb 0..7][lane][i]:   d = nb*16+(lane&15); k = ks*32+8*(lane>>4)+i; val = Wn2[k][d]
__global__ void prep_kernel(const float* __restrict__ We1, const float* __restrict__ We2,
                            const float* __restrict__ Wn1, const float* __restrict__ Wn2,
                            unsigned short* __restrict__ W1pack, unsigned short* __restrict__ W2p2,
                            unsigned short* __restrict__ Wn1p, unsigned short* __restrict__ Wn2p) {
    int tid = blockIdx.x * 256 + threadIdx.x;
    int stride = gridDim.x * 256;
    for (int p = tid; p < 9 * 36 * 64 * 8; p += stride) {
        int i = p & 7, lane = (p >> 3) & 63, rest = p >> 9;
        int nb = rest % 36, ks = rest / 36;
        int n = nb * 16 + (lane & 15);
        int k = ks * 32 + 8 * (lane >> 4) + i;
        W1pack[p] = (k < 257 && n < 514) ? f2bf(We1[k * 514 + n]) : (unsigned short)0;
    }
    for (int p = tid; p < 4 * 5 * 64 * 8; p += stride) {
        int i = p & 7, lane = (p >> 3) & 63, rest = p >> 9;
        int ks2 = rest % 5, wn = rest / 5;
        int g = lane >> 4, f = lane & 15;
        int nloc = ks2 * 32 + 16 * (i >> 2) + 4 * g + (i & 3);
        int ng = wn * 144 + nloc;
        W2p2[p] = (nloc < 144 && ng < 514) ? f2bf(We2[ng * 16 + f]) : (unsigned short)0;
    }
    for (int p = tid; p < 5 * 16 * 64 * 8; p += stride) {
        int i = p & 7, lane = (p >> 3) & 63, rest = p >> 9;
        int nb = rest % 16, ks = rest / 16;
        int u = nb * 16 + (lane & 15);
        int k = ks * 32 + 8 * (lane >> 4) + i;
        Wn1p[p] = (k < 144) ? f2bf(Wn1[k * 256 + u]) : (unsigned short)0;
    }
    for (int p = tid; p < 8 * 8 * 64 * 8; p += stride) {
        int i = p & 7, lane = (p >> 3) & 63, rest = p >> 9;
        int nb = rest % 8, ks = rest / 8;
        int d = nb * 16 + (lane & 15);
        int k = ks * 32 + 8 * (lane >> 4) + i;
        Wn2p[p] = f2bf(Wn2[k * 128 + d]);
    }
}

// ---------------------------------------------------------------- kNN v4: register dists + (bits,j) candidate pairs
// (R13 exact — proven; standalone runs at ~82% occupancy which the R14 fusion destroyed.)
#define EQCAP 36
#define CANDCAP 1024
__global__ __launch_bounds__(256) void knn_kernel(const float* __restrict__ x,
                                                  int* __restrict__ idx_o,
                                                  float* __restrict__ relk_o,
                                                  float* __restrict__ distk_o) {
    __shared__ unsigned hist[4][256];
    __shared__ unsigned wsum[4];
    __shared__ unsigned sel[2];
    __shared__ unsigned shA, shB;
    __shared__ int out_j[KK];
    __shared__ int eqbuf[EQCAP];
    __shared__ uint2 cand[CANDCAP];

    const int t = threadIdx.x;
    const int ln = t & 63, wv = t >> 6;
    const int gn = blockIdx.x;
    const int b = gn >> 12, i = gn & 4095;
    const float* xb = x + (size_t)b * NNODE * 3;
    const float xi0 = xb[3 * i], xi1 = xb[3 * i + 1], xi2 = xb[3 * i + 2];

    #pragma unroll
    for (int q2 = 0; q2 < 4; ++q2) hist[q2][t] = 0;
    __syncthreads();

    // ---- pass 1: dists into regs + round-0 (top byte) histogram
    unsigned ub[16];
    #pragma unroll
    for (int s = 0; s < 16; ++s) {
        float d = dist3(xi0, xi1, xi2, xb, t + 256 * s);
        ub[s] = __float_as_uint(d);
        atomicAdd(&hist[wv][ub[s] >> 24], 1u);
    }
    __syncthreads();

    int kk = KK;
    // ---- select round 0
    {
        unsigned hv = hist[0][t] + hist[1][t] + hist[2][t] + hist[3][t];
        unsigned v = hv;
        #pragma unroll
        for (int off = 1; off < 64; off <<= 1) {
            unsigned o = __shfl_up(v, off, 64);
            if (ln >= off) v += o;
        }
        if (ln == 63) wsum[wv] = v;
        __syncthreads();
        unsigned add = 0;
        #pragma unroll
        for (int w = 0; w < 4; ++w) add += (w < wv) ? wsum[w] : 0u;
        unsigned incl = v + add, excl = incl - hv;
        if ((unsigned)kk > excl && (unsigned)kk <= incl) { sel[0] = (unsigned)t; sel[1] = (unsigned)kk - excl; }
        __syncthreads();
    }
    unsigned prefix = sel[0];
    kk = (int)sel[1];
    __syncthreads();

    // ---- pass 2 (regs): packed count (winners<<16 | candidates), prefix-scan, write
    unsigned pc = 0;
    #pragma unroll
    for (int s = 0; s < 16; ++s) {
        unsigned tb = ub[s] >> 24;
        pc += (tb < prefix) ? 0x10000u : (tb == prefix ? 1u : 0u);
    }
    {
        unsigned v = pc;
        #pragma unroll
        for (int off = 1; off < 64; off <<= 1) {
            unsigned o = __shfl_up(v, off, 64);
            if (ln >= off) v += o;
        }
        if (ln == 63) wsum[wv] = v;
        __syncthreads();
        unsigned add = 0;
        #pragma unroll
        for (int w = 0; w < 4; ++w) add += (w < wv) ? wsum[w] : 0u;
        unsigned incl = v + add, excl = incl - pc;
        if (t == 255) { shA = incl >> 16; shB = incl & 0xFFFFu; }
        __syncthreads();
        unsigned wl = excl >> 16, wc = excl & 0xFFFFu;
        #pragma unroll
        for (int s = 0; s < 16; ++s) {
            unsigned u = ub[s];
            unsigned tb = u >> 24;
            int j = t + 256 * s;
            if (tb < prefix) { out_j[wl++] = j; }
            else if (tb == prefix) { if (wc < CANDCAP) cand[wc] = make_uint2(u, (unsigned)j); ++wc; }
        }
    }
    __syncthreads();
    const unsigned totL0 = shA, totC = shB;
    const bool fullscan = (totC > CANDCAP);

    // ---- rounds 1..3 over candidate pairs (or reg fallback)
    for (int r = 1; r < 4; ++r) {
        const int sh = 24 - 8 * r;
        #pragma unroll
        for (int q2 = 0; q2 < 4; ++q2) hist[q2][t] = 0;
        __syncthreads();
        if (!fullscan) {
            for (int ii = t; ii < (int)totC; ii += 256) {
                unsigned u = cand[ii].x;
                if ((u >> (sh + 8)) == prefix) atomicAdd(&hist[wv][(u >> sh) & 255], 1u);
            }
        } else {
            #pragma unroll
            for (int s = 0; s < 16; ++s) {
                unsigned u = ub[s];
                if ((u >> (sh + 8)) == prefix) atomicAdd(&hist[wv][(u >> sh) & 255], 1u);
            }
        }
        __syncthreads();
        unsigned hv = hist[0][t] + hist[1][t] + hist[2][t] + hist[3][t];
        unsigned v = hv;
        #pragma unroll
        for (int off = 1; off < 64; off <<= 1) {
            unsigned o = __shfl_up(v, off, 64);
            if (ln >= off) v += o;
        }
        if (ln == 63) wsum[wv] = v;
        __syncthreads();
        unsigned add = 0;
        #pragma unroll
        for (int w = 0; w < 4; ++w) add += (w < wv) ? wsum[w] : 0u;
        unsigned incl = v + add, excl = incl - hv;
        if ((unsigned)kk > excl && (unsigned)kk <= incl) { sel[0] = (unsigned)t; sel[1] = (unsigned)kk - excl; }
        __syncthreads();
        prefix = (prefix << 8) | sel[0];
        kk = (int)sel[1];
        __syncthreads();
    }
    const unsigned T = prefix;

    // ---- final collection
    int totL;
    if (!fullscan) {
        unsigned pc2 = 0;
        for (int ii = t; ii < (int)totC; ii += 256) {
            unsigned u = cand[ii].x;
            pc2 += (u < T) ? 0x10000u : (u == T ? 1u : 0u);
        }
        unsigned v = pc2;
        #pragma unroll
        for (int off = 1; off < 64; off <<= 1) {
            unsigned o = __shfl_up(v, off, 64);
            if (ln >= off) v += o;
        }
        if (ln == 63) wsum[wv] = v;
        __syncthreads();
        unsigned add = 0;
        #pragma unroll
        for (int w = 0; w < 4; ++w) add += (w < wv) ? wsum[w] : 0u;
        unsigned incl = v + add, excl = incl - pc2;
        if (t == 255) { shA = incl >> 16; shB = incl & 0xFFFFu; }
        __syncthreads();
        unsigned w2 = totL0 + (excl >> 16), we = excl & 0xFFFFu;
        for (int ii = t; ii < (int)totC; ii += 256) {
            unsigned u = cand[ii].x;
            int j = (int)cand[ii].y;
            if (u < T) { out_j[w2++] = j; }
            else if (u == T) { if (we < EQCAP) eqbuf[we] = j; ++we; }
        }
        __syncthreads();
        totL = (int)(totL0 + shA);
        const unsigned totE = shB;
        if (t == 0) {
            int need = KK - totL;
            if (totE <= EQCAP) {
                for (int a = 1; a < (int)totE; ++a) {
                    int key = eqbuf[a], c = a - 1;
                    while (c >= 0 && eqbuf[c] > key) { eqbuf[c + 1] = eqbuf[c]; --c; }
                    eqbuf[c + 1] = key;
                }
                for (int q = 0; q < need; ++q) out_j[totL + q] = eqbuf[q];
            } else {
                int taken = 0;
                for (int j = 0; j < NNODE && taken < need; ++j)
                    if (__float_as_uint(dist3(xi0, xi1, xi2, xb, j)) == T) out_j[totL + taken++] = j;
            }
        }
    } else {
        // exact reg-based full collection (overwrites out_j deterministically)
        unsigned pc2 = 0;
        #pragma unroll
        for (int s = 0; s < 16; ++s) {
            unsigned u = ub[s];
            pc2 += (u < T) ? 0x10000u : (u == T ? 1u : 0u);
        }
        unsigned v = pc2;
        #pragma unroll
        for (int off = 1; off < 64; off <<= 1) {
            unsigned o = __shfl_up(v, off, 64);
            if (ln >= off) v += o;
        }
        if (ln == 63) wsum[wv] = v;
        __syncthreads();
        unsigned add = 0;
        #pragma unroll
        for (int w = 0; w < 4; ++w) add += (w < wv) ? wsum[w] : 0u;
        unsigned incl = v + add, excl = incl - pc2;
        if (t == 255) { shA = incl >> 16; shB = incl & 0xFFFFu; }
        __syncthreads();
        unsigned w2 = excl >> 16, we = excl & 0xFFFFu;
        #pragma unroll
        for (int s = 0; s < 16; ++s) {
            unsigned u = ub[s];
            int j = t + 256 * s;
            if (u < T) { out_j[w2++] = j; }
            else if (u == T) { if (we < EQCAP) eqbuf[we] = j; ++we; }
        }
        __syncthreads();
        totL = (int)shA;
        const unsigned totE = shB;
        if (t == 0) {
            int need = KK - totL;
            if (totE <= EQCAP) {
                for (int a = 1; a < (int)totE; ++a) {
                    int key = eqbuf[a], c = a - 1;
                    while (c >= 0 && eqbuf[c] > key) { eqbuf[c + 1] = eqbuf[c]; --c; }
                    eqbuf[c + 1] = key;
                }
                for (int q = 0; q < need; ++q) out_j[totL + q] = eqbuf[q];
            } else {
                int taken = 0;
                for (int j = 0; j < NNODE && taken < need; ++j)
                    if (__float_as_uint(dist3(xi0, xi1, xi2, xb, j)) == T) out_j[totL + taken++] = j;
            }
        }
    }
    __syncthreads();

    if (t < KK) {
        int j = out_j[t];
        size_t eo = (size_t)gn * KK + t;
        idx_o[eo] = j;
        float r0 = __fsub_rn(xi0, xb[3 * j]);
        float r1 = __fsub_rn(xi1, xb[3 * j + 1]);
        float r2 = __fsub_rn(xi2, xb[3 * j + 2]);
        relk_o[eo * 3 + 0] = r0;
        relk_o[eo * 3 + 1] = r1;
        relk_o[eo * 3 + 2] = r2;
        distk_o[eo] = __fadd_rn(__fadd_rn(__fmul_rn(r0, r0), __fmul_rn(r1, r1)), __fmul_rn(r2, r2));
    }
}

// ---------------------------------------------------------------- edge MLP via MFMA + coors (R9/R13 exact — proven 229us)
// 256,2 is the ONLY non-spilling tier for this loop (R4-R7,R10: caps 102/128/170 all spill).
// R14 lesson: fusing kNN in here kills kNN occupancy (2 blk/CU vs ~8) — keep them separate.
__global__ __launch_bounds__(256, 2) void edge_kernel(
    const float* __restrict__ h, const float* __restrict__ x, const int* __restrict__ mask,
    const float* __restrict__ be1, const float* __restrict__ be2,
    const float* __restrict__ Wc1, const float* __restrict__ bc1,
    const float* __restrict__ Wc2, const float* __restrict__ bc2,
    const int* __restrict__ idx, const float* __restrict__ relk, const float* __restrict__ distk,
    const unsigned short* __restrict__ W1pack, const unsigned short* __restrict__ W2p2,
    float* __restrict__ m_i_out, float* __restrict__ coors_out)
{
    __shared__ unsigned short E2[64][168];
    __shared__ unsigned short hi_s[2][136];
    __shared__ float be1s[576];
    __shared__ int   j_s[64];
    __shared__ float cw_s[64];
    __shared__ float m_s4[4 * 64 * 16];
    __shared__ float m_sF[64 * 17];

    const int t = threadIdx.x;
    const int gn0 = blockIdx.x * 2;
    const int b = gn0 >> 12;
    const int wn = t >> 6, lane = t & 63;
    const int l15 = lane & 15, g = lane >> 4;

    if (t < 64) {
        size_t eo = (size_t)gn0 * KK + t;
        j_s[t] = idx[eo];
        float dv = distk[eo];
        ushort2* p = (ushort2*)&E2[t][128];
        p[0] = make_ushort2(f2bf(dv), 0);
        #pragma unroll
        for (int z = 1; z < 20; ++z) p[z] = make_ushort2(0, 0);
    }
    {
        int n = t >> 7, c = t & 127;
        hi_s[n][c] = f2bf(h[(size_t)(gn0 + n) * DD + c]);
    }
    for (int i2 = t; i2 < 576; i2 += 256) be1s[i2] = (i2 < 514) ? be1[i2] : 0.f;
    __syncthreads();

    for (int q = t; q < 64 * 32; q += 256) {
        int e = q >> 5, d4 = q & 31;
        int j = j_s[e];
        float4 v = *(const float4*)(h + ((size_t)b * NNODE + j) * DD + d4 * 4);
        *(uint2*)&E2[e][d4 * 4] = make_uint2(pk2(v.x, v.y), pk2(v.z, v.w));
    }
    __syncthreads();

    const bf16x8* W1v = (const bf16x8*)W1pack;
    const bf16x8* W2v = (const bf16x8*)W2p2;
    int erow[4];
    #pragma unroll
    for (int et = 0; et < 4; ++et) erow[et] = et * 16 + l15;

    f32x4 acc2[4];
    #pragma unroll
    for (int et = 0; et < 4; ++et)
        #pragma unroll
        for (int r = 0; r < 4; ++r) acc2[et][r] = 0.f;

    #pragma unroll
    for (int c = 0; c < 2; ++c) {
        f32x4 acc[4][4];
        #pragma unroll
        for (int nb = 0; nb < 4; ++nb)
            #pragma unroll
            for (int et = 0; et < 4; ++et)
                #pragma unroll
                for (int r = 0; r < 4; ++r) acc[nb][et][r] = 0.f;
        #pragma unroll
        for (int ks = 0; ks < 9; ++ks) {
            const bf16x8* wp = W1v + ((size_t)(ks * 36 + wn * 9 + c * 4)) * 64 + lane;
            bf16x8 afr[4];
            #pragma unroll
            for (int nb = 0; nb < 4; ++nb) afr[nb] = wp[nb * 64];
            bf16x8 bfr[4];
            if (ks < 4) {
                bf16x8 b0 = *(const bf16x8*)&hi_s[0][ks * 32 + 8 * g];
                bf16x8 b1 = *(const bf16x8*)&hi_s[1][ks * 32 + 8 * g];
                bfr[0] = b0; bfr[1] = b0; bfr[2] = b1; bfr[3] = b1;
            } else {
                #pragma unroll
                for (int et = 0; et < 4; ++et)
                    bfr[et] = *(const bf16x8*)&E2[erow[et]][(ks - 4) * 32 + 8 * g];
            }
            #pragma unroll
            for (int nb = 0; nb < 4; ++nb)
                #pragma unroll
                for (int et = 0; et < 4; ++et)
                    acc[nb][et] = __builtin_amdgcn_mfma_f32_16x16x32_bf16(afr[nb], bfr[et], acc[nb][et], 0, 0, 0);
        }
        #pragma unroll
        for (int nb = 0; nb < 4; ++nb) {
            f32x4 bv = *(const f32x4*)&be1s[wn * 144 + (c * 4 + nb) * 16 + 4 * g];
            #pragma unroll
            for (int et = 0; et < 4; ++et)
                #pragma unroll
                for (int r = 0; r < 4; ++r)
                    acc[nb][et][r] = silu_f(acc[nb][et][r] + bv[r]);
        }
        #pragma unroll
        for (int qq = 0; qq < 2; ++qq) {
            int ks2 = 2 * c + qq;
            bf16x8 a2 = W2v[(size_t)(wn * 5 + ks2) * 64 + lane];
            #pragma unroll
            for (int et = 0; et < 4; ++et) {
                union { unsigned u[4]; bf16x8 v; } cv;
                cv.u[0] = pk2(acc[2 * qq][et][0], acc[2 * qq][et][1]);
                cv.u[1] = pk2(acc[2 * qq][et][2], acc[2 * qq][et][3]);
                cv.u[2] = pk2(acc[2 * qq + 1][et][0], acc[2 * qq + 1][et][1]);
                cv.u[3] = pk2(acc[2 * qq + 1][et][2], acc[2 * qq + 1][et][3]);
                acc2[et] = __builtin_amdgcn_mfma_f32_16x16x32_bf16(a2, cv.v, acc2[et], 0, 0, 0);
            }
        }
    }
    {
        f32x4 acc8[4];
        #pragma unroll
        for (int et = 0; et < 4; ++et)
            #pragma unroll
            for (int r = 0; r < 4; ++r) acc8[et][r] = 0.f;
        #pragma unroll
        for (int ks = 0; ks < 9; ++ks) {
            bf16x8 af = W1v[((size_t)(ks * 36 + wn * 9 + 8)) * 64 + lane];
            bf16x8 bfr[4];
            if (ks < 4) {
                bf16x8 b0 = *(const bf16x8*)&hi_s[0][ks * 32 + 8 * g];
                bf16x8 b1 = *(const bf16x8*)&hi_s[1][ks * 32 + 8 * g];
                bfr[0] = b0; bfr[1] = b0; bfr[2] = b1; bfr[3] = b1;
            } else {
                #pragma unroll
                for (int et = 0; et < 4; ++et)
                    bfr[et] = *(const bf16x8*)&E2[erow[et]][(ks - 4) * 32 + 8 * g];
            }
            #pragma unroll
            for (int et = 0; et < 4; ++et)
                acc8[et] = __builtin_amdgcn_mfma_f32_16x16x32_bf16(af, bfr[et], acc8[et], 0, 0, 0);
        }
        f32x4 bv = *(const f32x4*)&be1s[wn * 144 + 128 + 4 * g];
        #pragma unroll
        for (int et = 0; et < 4; ++et)
            #pragma unroll
            for (int r = 0; r < 4; ++r)
                acc8[et][r] = silu_f(acc8[et][r] + bv[r]);
        bf16x8 a2 = W2v[(size_t)(wn * 5 + 4) * 64 + lane];
        #pragma unroll
        for (int et = 0; et < 4; ++et) {
            union { unsigned u[4]; bf16x8 v; } cv;
            cv.u[0] = pk2(acc8[et][0], acc8[et][1]);
            cv.u[1] = pk2(acc8[et][2], acc8[et][3]);
            cv.u[2] = 0; cv.u[3] = 0;
            acc2[et] = __builtin_amdgcn_mfma_f32_16x16x32_bf16(a2, cv.v, acc2[et], 0, 0, 0);
        }
    }
    #pragma unroll
    for (int et = 0; et < 4; ++et)
        *(f32x4*)&m_s4[((wn * 64) + erow[et]) * 16 + 4 * g] = acc2[et];
    __syncthreads();

    #pragma unroll
    for (int i2 = t; i2 < 64 * 16; i2 += 256) {
        int e = i2 >> 4, f = i2 & 15;
        float s = m_s4[e * 16 + f] + m_s4[(64 + e) * 16 + f]
                + m_s4[(128 + e) * 16 + f] + m_s4[(192 + e) * 16 + f];
        m_sF[e * 17 + f] = silu_f(s + be2[f]);
    }
    __syncthreads();

    {
        const int ee = t >> 2, q4 = t & 3;
        const int u0 = q4 * 16;
        float mm[16];
        #pragma unroll
        for (int f = 0; f < 16; ++f) mm[f] = m_sF[ee * 17 + f];
        float h2[16];
        {
            const float4* bp = (const float4*)(bc1 + u0);
            float4 b0 = bp[0], b1 = bp[1], b2v = bp[2], b3 = bp[3];
            h2[0]=b0.x; h2[1]=b0.y; h2[2]=b0.z; h2[3]=b0.w;
            h2[4]=b1.x; h2[5]=b1.y; h2[6]=b1.z; h2[7]=b1.w;
            h2[8]=b2v.x; h2[9]=b2v.y; h2[10]=b2v.z; h2[11]=b2v.w;
            h2[12]=b3.x; h2[13]=b3.y; h2[14]=b3.z; h2[15]=b3.w;
        }
        #pragma unroll
        for (int f = 0; f < 16; ++f) {
            const float4* wp = (const float4*)(Wc1 + (size_t)f * 64 + u0);
            float4 w0 = wp[0], w1 = wp[1], w2 = wp[2], w3 = wp[3];
            float v = mm[f];
            h2[0]  = fmaf(v, w0.x, h2[0]);  h2[1]  = fmaf(v, w0.y, h2[1]);
            h2[2]  = fmaf(v, w0.z, h2[2]);  h2[3]  = fmaf(v, w0.w, h2[3]);
            h2[4]  = fmaf(v, w1.x, h2[4]);  h2[5]  = fmaf(v, w1.y, h2[5]);
            h2[6]  = fmaf(v, w1.z, h2[6]);  h2[7]  = fmaf(v, w1.w, h2[7]);
            h2[8]  = fmaf(v, w2.x, h2[8]);  h2[9]  = fmaf(v, w2.y, h2[9]);
            h2[10] = fmaf(v, w2.z, h2[10]); h2[11] = fmaf(v, w2.w, h2[11]);
            h2[12] = fmaf(v, w3.x, h2[12]); h2[13] = fmaf(v, w3.y, h2[13]);
            h2[14] = fmaf(v, w3.z, h2[14]); h2[15] = fmaf(v, w3.w, h2[15]);
        }
        float cw = 0.f;
        const float4* cp = (const float4*)(Wc2 + u0);
        float4 c0 = cp[0], c1 = cp[1], c2 = cp[2], c3 = cp[3];
        const float wv[16] = {c0.x,c0.y,c0.z,c0.w, c1.x,c1.y,c1.z,c1.w,
                              c2.x,c2.y,c2.z,c2.w, c3.x,c3.y,c3.z,c3.w};
        #pragma unroll
        for (int r = 0; r < 16; ++r) cw = fmaf(silu_f(h2[r]), wv[r], cw);
        cw += __shfl_xor(cw, 1, 64);
        cw += __shfl_xor(cw, 2, 64);
        if (q4 == 0) {
            cw += bc2[0];
            int gnode = gn0 + (ee >> 5);
            int mi = mask[gnode];
            int mj = mask[b * NNODE + j_s[ee]];
            cw_s[ee] = (mi != 0 && mj != 0) ? cw : 0.f;
        }
    }
    __syncthreads();

    if (t < 32) {
        int n = t >> 4, f = t & 15;
        float s = 0.f;
        #pragma unroll
        for (int k2 = 0; k2 < 32; ++k2) s += m_sF[(n * 32 + k2) * 17 + f];
        m_i_out[(size_t)(gn0 + n) * CFX + f] = s;
    } else if (t < 38) {
        int r = t - 32;
        int n = r / 3, c = r - n * 3;
        const float* rp = relk + ((size_t)gn0 * KK + n * 32) * 3 + c;
        float s = 0.f;
        #pragma unroll
        for (int k2 = 0; k2 < 32; ++k2) s = fmaf(cw_s[n * 32 + k2], rp[k2 * 3], s);
        coors_out[(size_t)(gn0 + n) * 3 + c] = s + x[(size_t)(gn0 + n) * 3 + c];
    }
}

// ---------------------------------------------------------------- node MLP via MFMA (R11 exact — proven)
__global__ __launch_bounds__(256) void node_kernel(
    const float* __restrict__ h, const float* __restrict__ m_i,
    const unsigned short* __restrict__ Wn1p, const float* __restrict__ bn1,
    const unsigned short* __restrict__ Wn2p, const float* __restrict__ bn2,
    float* __restrict__ node_out)
{
    __shared__ unsigned short nin[32][168];
    __shared__ unsigned short hid[32][264];

    const int t = threadIdx.x;
    const int gn0 = blockIdx.x * 32;
    const int wn = t >> 6, lane = t & 63;
    const int l15 = lane & 15, g = lane >> 4;

    for (int q = t; q < 32 * 32; q += 256) {
        int node = q >> 5, c4 = q & 31;
        float4 v = *(const float4*)(h + (size_t)(gn0 + node) * DD + c4 * 4);
        *(uint2*)&nin[node][c4 * 4] = make_uint2(pk2(v.x, v.y), pk2(v.z, v.w));
    }
    if (t < 128) {
        int node = t >> 2, c4 = t & 3;
        float4 v = *(const float4*)(m_i + (size_t)(gn0 + node) * CFX + c4 * 4);
        *(uint2*)&nin[node][128 + c4 * 4] = make_uint2(pk2(v.x, v.y), pk2(v.z, v.w));
    } else if (t < 224) {
        int r = t - 128;
        int node = r / 3, cc = (r - node * 3) * 8;
        *(uint4*)&nin[node][144 + cc] = make_uint4(0, 0, 0, 0);
    }
    __syncthreads();

    const bf16x8* A1 = (const bf16x8*)Wn1p;
    f32x4 acc[4][2];
    #pragma unroll
    for (int nb = 0; nb < 4; ++nb)
        #pragma unroll
        for (int et = 0; et < 2; ++et)
            #pragma unroll
            for (int r = 0; r < 4; ++r) acc[nb][et][r] = 0.f;
    #pragma unroll
    for (int ks = 0; ks < 5; ++ks) {
        const bf16x8* wp = A1 + ((size_t)(ks * 16 + wn * 4)) * 64 + lane;
        bf16x8 afr[4];
        #pragma unroll
        for (int nb = 0; nb < 4; ++nb) afr[nb] = wp[nb * 64];
        bf16x8 b0 = *(const bf16x8*)&nin[l15][ks * 32 + 8 * g];
        bf16x8 b1 = *(const bf16x8*)&nin[16 + l15][ks * 32 + 8 * g];
        #pragma unroll
        for (int nb = 0; nb < 4; ++nb) {
            acc[nb][0] = __builtin_amdgcn_mfma_f32_16x16x32_bf16(afr[nb], b0, acc[nb][0], 0, 0, 0);
            acc[nb][1] = __builtin_amdgcn_mfma_f32_16x16x32_bf16(afr[nb], b1, acc[nb][1], 0, 0, 0);
        }
    }
    #pragma unroll
    for (int nb = 0; nb < 4; ++nb) {
        int u0 = (wn * 4 + nb) * 16 + 4 * g;
        f32x4 bv = *(const f32x4*)&bn1[u0];
        #pragma unroll
        for (int et = 0; et < 2; ++et) {
            float s0 = silu_f(acc[nb][et][0] + bv[0]);
            float s1 = silu_f(acc[nb][et][1] + bv[1]);
            float s2 = silu_f(acc[nb][et][2] + bv[2]);
            float s3 = silu_f(acc[nb][et][3] + bv[3]);
            *(uint2*)&hid[et * 16 + l15][u0] = make_uint2(pk2(s0, s1), pk2(s2, s3));
        }
    }
    __syncthreads();

    const bf16x8* A2 = (const bf16x8*)Wn2p;
    f32x4 acc2[2][2];
    #pragma unroll
    for (int nb = 0; nb < 2; ++nb)
        #pragma unroll
        for (int et = 0; et < 2; ++et)
            #pragma unroll
            for (int r = 0; r < 4; ++r) acc2[nb][et][r] = 0.f;
    #pragma unroll
    for (int ks = 0; ks < 8; ++ks) {
        const bf16x8* wp = A2 + ((size_t)(ks * 8 + wn * 2)) * 64 + lane;
        bf16x8 a0 = wp[0], a1 = wp[64];
        bf16x8 b0 = *(const bf16x8*)&hid[l15][ks * 32 + 8 * g];
        bf16x8 b1 = *(const bf16x8*)&hid[16 + l15][ks * 32 + 8 * g];
        acc2[0][0] = __builtin_amdgcn_mfma_f32_16x16x32_bf16(a0, b0, acc2[0][0], 0, 0, 0);
        acc2[0][1] = __builtin_amdgcn_mfma_f32_16x16x32_bf16(a0, b1, acc2[0][1], 0, 0, 0);
        acc2[1][0] = __builtin_amdgcn_mfma_f32_16x16x32_bf16(a1, b0, acc2[1][0], 0, 0, 0);
        acc2[1][1] = __builtin_amdgcn_mfma_f32_16x16x32_bf16(a1, b1, acc2[1][1], 0, 0, 0);
    }
    #pragma unroll
    for (int nb = 0; nb < 2; ++nb) {
        int d0 = (wn * 2 + nb) * 16 + 4 * g;
        f32x4 bv = *(const f32x4*)&bn2[d0];
        #pragma unroll
        for (int et = 0; et < 2; ++et) {
            int gnode = gn0 + et * 16 + l15;
            float4 hv = *(const float4*)(h + (size_t)gnode * DD + d0);
            float4 o;
            o.x = acc2[nb][et][0] + bv[0] + hv.x;
            o.y = acc2[nb][et][1] + bv[1] + hv.y;
            o.z = acc2[nb][et][2] + bv[2] + hv.z;
            o.w = acc2[nb][et][3] + bv[3] + hv.w;
            *(float4*)(node_out + (size_t)gnode * DD + d0) = o;
        }
    }
}

// ---------------------------------------------------------------- launch
extern "C" void kernel_launch(void* const* d_in, const int* in_sizes, int n_in,
                              void* d_out, int out_size, void* d_ws, size_t ws_size,
                              hipStream_t stream) {
    const float* h   = (const float*)d_in[0];
    const float* x   = (const float*)d_in[1];
    const int*   mask= (const int*)d_in[2];
    const float* We1 = (const float*)d_in[3];
    const float* be1 = (const float*)d_in[4];
    const float* We2 = (const float*)d_in[5];
    const float* be2 = (const float*)d_in[6];
    const float* Wc1 = (const float*)d_in[7];
    const float* bc1 = (const float*)d_in[8];
    const float* Wc2 = (const float*)d_in[9];
    const float* bc2 = (const float*)d_in[10];
    const float* Wn1 = (const float*)d_in[11];
    const float* bn1 = (const float*)d_in[12];
    const float* Wn2 = (const float*)d_in[13];
    const float* bn2 = (const float*)d_in[14];

    float* node_out  = (float*)d_out;
    float* coors_out = node_out + (size_t)BB * NNODE * DD;

    char* ws = (char*)d_ws;
    int*   idx    = (int*)ws;            ws += (size_t)BB * NNODE * KK * 4;
    float* relk   = (float*)ws;          ws += (size_t)BB * NNODE * KK * 3 * 4;
    float* distk  = (float*)ws;          ws += (size_t)BB * NNODE * KK * 4;
    float* m_i    = (float*)ws;          ws += (size_t)BB * NNODE * CFX * 4;
    unsigned short* W1pack = (unsigned short*)ws;  ws += (size_t)9 * 36 * 64 * 8 * 2;
    unsigned short* W2p2   = (unsigned short*)ws;  ws += (size_t)4 * 5 * 64 * 8 * 2;
    unsigned short* Wn1p   = (unsigned short*)ws;  ws += (size_t)5 * 16 * 64 * 8 * 2;
    unsigned short* Wn2p   = (unsigned short*)ws;  ws += (size_t)8 * 8 * 64 * 8 * 2;

    prep_kernel<<<256, 256, 0, stream>>>(We1, We2, Wn1, Wn2, W1pack, W2p2, Wn1p, Wn2p);
    knn_kernel<<<BB * NNODE, 256, 0, stream>>>(x, idx, relk, distk);
    edge_kernel<<<BB * NNODE / 2, 256, 0, stream>>>(h, x, mask, be1, be2, Wc1, bc1, Wc2, bc2,
                                                    idx, relk, distk, W1pack, W2p2,
                                                    m_i, coors_out);
    node_kernel<<<BB * NNODE / 32, 256, 0, stream>>>(h, m_i, Wn1p, bn1, Wn2p, bn2, node_out);
}

// Round 16
// 288.008 us; speedup vs baseline: 1.2523x; 1.1400x over previous
//
#include <hip/hip_runtime.h>
#include <hip/hip_bf16.h>

// Problem constants (fixed by reference)
#define BB    2
#define NNODE 4096
#define DD    128
#define KK    32
#define CFX   16

typedef __attribute__((ext_vector_type(8))) short bf16x8;
typedef __attribute__((ext_vector_type(4))) float f32x4;

__device__ __forceinline__ unsigned short f2bf(float f) {
    __hip_bfloat16 h = __float2bfloat16(f);
    return *reinterpret_cast<unsigned short*>(&h);
}
__device__ __forceinline__ unsigned pk2(float lo, float hi) {
    __hip_bfloat162 v = __float22bfloat162_rn(make_float2(lo, hi));
    return *reinterpret_cast<unsigned*>(&v);
}
// Fast silu: v * rcp(1+e^-v) — ~1ulp rcp vs full IEEE divide; output bf16-rounded anyway.
__device__ __forceinline__ float silu_f(float v) {
    float e = __expf(-v);
    return v * __builtin_amdgcn_rcpf(1.f + e);
}
// Exact dist (matches reference mul-then-add, no FMA contraction) — bit-identical everywhere.
__device__ __forceinline__ float dist3(float xi0, float xi1, float xi2,
                                       const float* __restrict__ xb, int j) {
    float d0 = __fsub_rn(xi0, xb[3 * j]);
    float d1 = __fsub_rn(xi1, xb[3 * j + 1]);
    float d2 = __fsub_rn(xi2, xb[3 * j + 2]);
    return __fadd_rn(__fadd_rn(__fmul_rn(d0, d0), __fmul_rn(d1, d1)), __fmul_rn(d2, d2));
}

// ---------------------------------------------------------------- prep: pack weights into MFMA fragment layout
// W1pack[ks 0..8][nbg 0..35][lane][i]: n = nbg*16+(lane&15); k = ks*32+8*(lane>>4)+i
//   (ks 0..3 = h_i rows, consumed by pre_kernel; ks 4..8 = h_j/dist rows, consumed by edge)
// W2p2[wn 0..3][ks2 0..4][lane][i]:  f = lane&15; g=lane>>4; nloc = ks2*32+16*(i>>2)+4*g+(i&3); ng = wn*144+nloc
// Wn1p[ks 0..4][nb 0..15][lane][i]:  u = nb*16+(lane&15); k = ks*32+8*(lane>>4)+i; val = (k<144)?Wn1[k][u]:0
// Wn2p[ks 0..7][nb 0..7][lane][i]:   d = nb*16+(lane&15); k = ks*32+8*(lane>>4)+i; val = Wn2[k][d]
__global__ void prep_kernel(const float* __restrict__ We1, const float* __restrict__ We2,
                            const float* __restrict__ Wn1, const float* __restrict__ Wn2,
                            unsigned short* __restrict__ W1pack, unsigned short* __restrict__ W2p2,
                            unsigned short* __restrict__ Wn1p, unsigned short* __restrict__ Wn2p) {
    int tid = blockIdx.x * 256 + threadIdx.x;
    int stride = gridDim.x * 256;
    for (int p = tid; p < 9 * 36 * 64 * 8; p += stride) {
        int i = p & 7, lane = (p >> 3) & 63, rest = p >> 9;
        int nb = rest % 36, ks = rest / 36;
        int n = nb * 16 + (lane & 15);
        int k = ks * 32 + 8 * (lane >> 4) + i;
        W1pack[p] = (k < 257 && n < 514) ? f2bf(We1[k * 514 + n]) : (unsigned short)0;
    }
    for (int p = tid; p < 4 * 5 * 64 * 8; p += stride) {
        int i = p & 7, lane = (p >> 3) & 63, rest = p >> 9;
        int ks2 = rest % 5, wn = rest / 5;
        int g = lane >> 4, f = lane & 15;
        int nloc = ks2 * 32 + 16 * (i >> 2) + 4 * g + (i & 3);
        int ng = wn * 144 + nloc;
        W2p2[p] = (nloc < 144 && ng < 514) ? f2bf(We2[ng * 16 + f]) : (unsigned short)0;
    }
    for (int p = tid; p < 5 * 16 * 64 * 8; p += stride) {
        int i = p & 7, lane = (p >> 3) & 63, rest = p >> 9;
        int nb = rest % 16, ks = rest / 16;
        int u = nb * 16 + (lane & 15);
        int k = ks * 32 + 8 * (lane >> 4) + i;
        Wn1p[p] = (k < 144) ? f2bf(Wn1[k * 256 + u]) : (unsigned short)0;
    }
    for (int p = tid; p < 8 * 8 * 64 * 8; p += stride) {
        int i = p & 7, lane = (p >> 3) & 63, rest = p >> 9;
        int nb = rest % 8, ks = rest / 8;
        int d = nb * 16 + (lane & 15);
        int k = ks * 32 + 8 * (lane >> 4) + i;
        Wn2p[p] = f2bf(Wn2[k * 128 + d]);
    }
}

// ---------------------------------------------------------------- pre: per-node h_i half of edge GEMM1
// pre[node][n] = sum_{k<128} We1[k][n]*bf16(h_i[k]) + be1[n]  (n in 0..575; pad n: weights 0)
// Block = 16 nodes, 256 threads (4 waves); wave wn owns the 144-wide n-slice. K=128 = 4 ks.
// MFMA tiles are full (16 nodes = 16 B-columns) — 8x less work than recomputing per-edge.
__global__ __launch_bounds__(256) void pre_kernel(
    const float* __restrict__ h, const float* __restrict__ be1,
    const unsigned short* __restrict__ W1pack, float* __restrict__ pre_g)
{
    __shared__ unsigned short nin[16][136];
    const int t = threadIdx.x;
    const int gn0 = blockIdx.x * 16;
    const int wn = t >> 6, lane = t & 63;
    const int l15 = lane & 15, g = lane >> 4;

    for (int q = t; q < 16 * 32; q += 256) {
        int node = q >> 5, c4 = q & 31;
        float4 v = *(const float4*)(h + (size_t)(gn0 + node) * DD + c4 * 4);
        *(uint2*)&nin[node][c4 * 4] = make_uint2(pk2(v.x, v.y), pk2(v.z, v.w));
    }
    __syncthreads();

    const bf16x8* W1v = (const bf16x8*)W1pack;
    f32x4 acc[9];
    #pragma unroll
    for (int nb = 0; nb < 9; ++nb)
        #pragma unroll
        for (int r = 0; r < 4; ++r) acc[nb][r] = 0.f;
    #pragma unroll
    for (int ks = 0; ks < 4; ++ks) {
        bf16x8 bfr = *(const bf16x8*)&nin[l15][ks * 32 + 8 * g];
        #pragma unroll
        for (int nb = 0; nb < 9; ++nb) {
            bf16x8 af = W1v[((size_t)(ks * 36 + wn * 9 + nb)) * 64 + lane];
            acc[nb] = __builtin_amdgcn_mfma_f32_16x16x32_bf16(af, bfr, acc[nb], 0, 0, 0);
        }
    }
    // epilogue: + be1 (guarded), write [node][576] f32
    float* outp = pre_g + (size_t)(gn0 + l15) * 576;
    #pragma unroll
    for (int nb = 0; nb < 9; ++nb) {
        int n0 = wn * 144 + nb * 16 + 4 * g;
        float4 o;
        o.x = acc[nb][0] + ((n0 + 0) < 514 ? be1[n0 + 0] : 0.f);
        o.y = acc[nb][1] + ((n0 + 1) < 514 ? be1[n0 + 1] : 0.f);
        o.z = acc[nb][2] + ((n0 + 2) < 514 ? be1[n0 + 2] : 0.f);
        o.w = acc[nb][3] + ((n0 + 3) < 514 ? be1[n0 + 3] : 0.f);
        *(float4*)(outp + n0) = o;
    }
}

// ---------------------------------------------------------------- kNN v4 (R13 exact — proven)
#define EQCAP 36
#define CANDCAP 1024
__global__ __launch_bounds__(256) void knn_kernel(const float* __restrict__ x,
                                                  int* __restrict__ idx_o,
                                                  float* __restrict__ relk_o,
                                                  float* __restrict__ distk_o) {
    __shared__ unsigned hist[4][256];
    __shared__ unsigned wsum[4];
    __shared__ unsigned sel[2];
    __shared__ unsigned shA, shB;
    __shared__ int out_j[KK];
    __shared__ int eqbuf[EQCAP];
    __shared__ uint2 cand[CANDCAP];

    const int t = threadIdx.x;
    const int ln = t & 63, wv = t >> 6;
    const int gn = blockIdx.x;
    const int b = gn >> 12, i = gn & 4095;
    const float* xb = x + (size_t)b * NNODE * 3;
    const float xi0 = xb[3 * i], xi1 = xb[3 * i + 1], xi2 = xb[3 * i + 2];

    #pragma unroll
    for (int q2 = 0; q2 < 4; ++q2) hist[q2][t] = 0;
    __syncthreads();

    unsigned ub[16];
    #pragma unroll
    for (int s = 0; s < 16; ++s) {
        float d = dist3(xi0, xi1, xi2, xb, t + 256 * s);
        ub[s] = __float_as_uint(d);
        atomicAdd(&hist[wv][ub[s] >> 24], 1u);
    }
    __syncthreads();

    int kk = KK;
    {
        unsigned hv = hist[0][t] + hist[1][t] + hist[2][t] + hist[3][t];
        unsigned v = hv;
        #pragma unroll
        for (int off = 1; off < 64; off <<= 1) {
            unsigned o = __shfl_up(v, off, 64);
            if (ln >= off) v += o;
        }
        if (ln == 63) wsum[wv] = v;
        __syncthreads();
        unsigned add = 0;
        #pragma unroll
        for (int w = 0; w < 4; ++w) add += (w < wv) ? wsum[w] : 0u;
        unsigned incl = v + add, excl = incl - hv;
        if ((unsigned)kk > excl && (unsigned)kk <= incl) { sel[0] = (unsigned)t; sel[1] = (unsigned)kk - excl; }
        __syncthreads();
    }
    unsigned prefix = sel[0];
    kk = (int)sel[1];
    __syncthreads();

    unsigned pc = 0;
    #pragma unroll
    for (int s = 0; s < 16; ++s) {
        unsigned tb = ub[s] >> 24;
        pc += (tb < prefix) ? 0x10000u : (tb == prefix ? 1u : 0u);
    }
    {
        unsigned v = pc;
        #pragma unroll
        for (int off = 1; off < 64; off <<= 1) {
            unsigned o = __shfl_up(v, off, 64);
            if (ln >= off) v += o;
        }
        if (ln == 63) wsum[wv] = v;
        __syncthreads();
        unsigned add = 0;
        #pragma unroll
        for (int w = 0; w < 4; ++w) add += (w < wv) ? wsum[w] : 0u;
        unsigned incl = v + add, excl = incl - pc;
        if (t == 255) { shA = incl >> 16; shB = incl & 0xFFFFu; }
        __syncthreads();
        unsigned wl = excl >> 16, wc = excl & 0xFFFFu;
        #pragma unroll
        for (int s = 0; s < 16; ++s) {
            unsigned u = ub[s];
            unsigned tb = u >> 24;
            int j = t + 256 * s;
            if (tb < prefix) { out_j[wl++] = j; }
            else if (tb == prefix) { if (wc < CANDCAP) cand[wc] = make_uint2(u, (unsigned)j); ++wc; }
        }
    }
    __syncthreads();
    const unsigned totL0 = shA, totC = shB;
    const bool fullscan = (totC > CANDCAP);

    for (int r = 1; r < 4; ++r) {
        const int sh = 24 - 8 * r;
        #pragma unroll
        for (int q2 = 0; q2 < 4; ++q2) hist[q2][t] = 0;
        __syncthreads();
        if (!fullscan) {
            for (int ii = t; ii < (int)totC; ii += 256) {
                unsigned u = cand[ii].x;
                if ((u >> (sh + 8)) == prefix) atomicAdd(&hist[wv][(u >> sh) & 255], 1u);
            }
        } else {
            #pragma unroll
            for (int s = 0; s < 16; ++s) {
                unsigned u = ub[s];
                if ((u >> (sh + 8)) == prefix) atomicAdd(&hist[wv][(u >> sh) & 255], 1u);
            }
        }
        __syncthreads();
        unsigned hv = hist[0][t] + hist[1][t] + hist[2][t] + hist[3][t];
        unsigned v = hv;
        #pragma unroll
        for (int off = 1; off < 64; off <<= 1) {
            unsigned o = __shfl_up(v, off, 64);
            if (ln >= off) v += o;
        }
        if (ln == 63) wsum[wv] = v;
        __syncthreads();
        unsigned add = 0;
        #pragma unroll
        for (int w = 0; w < 4; ++w) add += (w < wv) ? wsum[w] : 0u;
        unsigned incl = v + add, excl = incl - hv;
        if ((unsigned)kk > excl && (unsigned)kk <= incl) { sel[0] = (unsigned)t; sel[1] = (unsigned)kk - excl; }
        __syncthreads();
        prefix = (prefix << 8) | sel[0];
        kk = (int)sel[1];
        __syncthreads();
    }
    const unsigned T = prefix;

    int totL;
    if (!fullscan) {
        unsigned pc2 = 0;
        for (int ii = t; ii < (int)totC; ii += 256) {
            unsigned u = cand[ii].x;
            pc2 += (u < T) ? 0x10000u : (u == T ? 1u : 0u);
        }
        unsigned v = pc2;
        #pragma unroll
        for (int off = 1; off < 64; off <<= 1) {
            unsigned o = __shfl_up(v, off, 64);
            if (ln >= off) v += o;
        }
        if (ln == 63) wsum[wv] = v;
        __syncthreads();
        unsigned add = 0;
        #pragma unroll
        for (int w = 0; w < 4; ++w) add += (w < wv) ? wsum[w] : 0u;
        unsigned incl = v + add, excl = incl - pc2;
        if (t == 255) { shA = incl >> 16; shB = incl & 0xFFFFu; }
        __syncthreads();
        unsigned w2 = totL0 + (excl >> 16), we = excl & 0xFFFFu;
        for (int ii = t; ii < (int)totC; ii += 256) {
            unsigned u = cand[ii].x;
            int j = (int)cand[ii].y;
            if (u < T) { out_j[w2++] = j; }
            else if (u == T) { if (we < EQCAP) eqbuf[we] = j; ++we; }
        }
        __syncthreads();
        totL = (int)(totL0 + shA);
        const unsigned totE = shB;
        if (t == 0) {
            int need = KK - totL;
            if (totE <= EQCAP) {
                for (int a = 1; a < (int)totE; ++a) {
                    int key = eqbuf[a], c = a - 1;
                    while (c >= 0 && eqbuf[c] > key) { eqbuf[c + 1] = eqbuf[c]; --c; }
                    eqbuf[c + 1] = key;
                }
                for (int q = 0; q < need; ++q) out_j[totL + q] = eqbuf[q];
            } else {
                int taken = 0;
                for (int j = 0; j < NNODE && taken < need; ++j)
                    if (__float_as_uint(dist3(xi0, xi1, xi2, xb, j)) == T) out_j[totL + taken++] = j;
            }
        }
    } else {
        unsigned pc2 = 0;
        #pragma unroll
        for (int s = 0; s < 16; ++s) {
            unsigned u = ub[s];
            pc2 += (u < T) ? 0x10000u : (u == T ? 1u : 0u);
        }
        unsigned v = pc2;
        #pragma unroll
        for (int off = 1; off < 64; off <<= 1) {
            unsigned o = __shfl_up(v, off, 64);
            if (ln >= off) v += o;
        }
        if (ln == 63) wsum[wv] = v;
        __syncthreads();
        unsigned add = 0;
        #pragma unroll
        for (int w = 0; w < 4; ++w) add += (w < wv) ? wsum[w] : 0u;
        unsigned incl = v + add, excl = incl - pc2;
        if (t == 255) { shA = incl >> 16; shB = incl & 0xFFFFu; }
        __syncthreads();
        unsigned w2 = excl >> 16, we = excl & 0xFFFFu;
        #pragma unroll
        for (int s = 0; s < 16; ++s) {
            unsigned u = ub[s];
            int j = t + 256 * s;
            if (u < T) { out_j[w2++] = j; }
            else if (u == T) { if (we < EQCAP) eqbuf[we] = j; ++we; }
        }
        __syncthreads();
        totL = (int)shA;
        const unsigned totE = shB;
        if (t == 0) {
            int need = KK - totL;
            if (totE <= EQCAP) {
                for (int a = 1; a < (int)totE; ++a) {
                    int key = eqbuf[a], c = a - 1;
                    while (c >= 0 && eqbuf[c] > key) { eqbuf[c + 1] = eqbuf[c]; --c; }
                    eqbuf[c + 1] = key;
                }
                for (int q = 0; q < need; ++q) out_j[totL + q] = eqbuf[q];
            } else {
                int taken = 0;
                for (int j = 0; j < NNODE && taken < need; ++j)
                    if (__float_as_uint(dist3(xi0, xi1, xi2, xb, j)) == T) out_j[totL + taken++] = j;
            }
        }
    }
    __syncthreads();

    if (t < KK) {
        int j = out_j[t];
        size_t eo = (size_t)gn * KK + t;
        idx_o[eo] = j;
        float r0 = __fsub_rn(xi0, xb[3 * j]);
        float r1 = __fsub_rn(xi1, xb[3 * j + 1]);
        float r2 = __fsub_rn(xi2, xb[3 * j + 2]);
        relk_o[eo * 3 + 0] = r0;
        relk_o[eo * 3 + 1] = r1;
        relk_o[eo * 3 + 2] = r2;
        distk_o[eo] = __fadd_rn(__fadd_rn(__fmul_rn(r0, r0), __fmul_rn(r1, r1)), __fmul_rn(r2, r2));
    }
}

// ---------------------------------------------------------------- edge MLP via MFMA + coors
// R13 structure with the h_i half of GEMM1 FACTORED OUT (per-node pre[] via C-in init):
// K drops 288->160 (ks 9->5), -44% MFMA + A-loads, no hi_s/be1s. GEMM2/epilogue unchanged.
// (256,2) = the only non-spilling tier (R4-R7,R10). R14: don't fuse kNN here.
__global__ __launch_bounds__(256, 2) void edge_kernel(
    const float* __restrict__ h, const float* __restrict__ x, const int* __restrict__ mask,
    const float* __restrict__ be2,
    const float* __restrict__ Wc1, const float* __restrict__ bc1,
    const float* __restrict__ Wc2, const float* __restrict__ bc2,
    const int* __restrict__ idx, const float* __restrict__ relk, const float* __restrict__ distk,
    const unsigned short* __restrict__ W1pack, const unsigned short* __restrict__ W2p2,
    const float* __restrict__ pre_g,
    float* __restrict__ m_i_out, float* __restrict__ coors_out)
{
    __shared__ unsigned short E2[64][168];
    __shared__ float pre_s[2 * 576];
    __shared__ int   j_s[64];
    __shared__ float cw_s[64];
    __shared__ float m_s4[4 * 64 * 16];
    __shared__ float m_sF[64 * 17];

    const int t = threadIdx.x;
    const int gn0 = blockIdx.x * 2;
    const int b = gn0 >> 12;
    const int wn = t >> 6, lane = t & 63;
    const int l15 = lane & 15, g = lane >> 4;

    if (t < 64) {
        size_t eo = (size_t)gn0 * KK + t;
        j_s[t] = idx[eo];
        float dv = distk[eo];
        ushort2* p = (ushort2*)&E2[t][128];
        p[0] = make_ushort2(f2bf(dv), 0);
        #pragma unroll
        for (int z = 1; z < 20; ++z) p[z] = make_ushort2(0, 0);
    }
    // stage pre for the 2 nodes (contiguous 1152 floats)
    {
        const float4* src = (const float4*)(pre_g + (size_t)gn0 * 576);
        float4* dst = (float4*)pre_s;
        for (int i2 = t; i2 < 288; i2 += 256) dst[i2] = src[i2];
    }
    __syncthreads();

    for (int q = t; q < 64 * 32; q += 256) {
        int e = q >> 5, d4 = q & 31;
        int j = j_s[e];
        float4 v = *(const float4*)(h + ((size_t)b * NNODE + j) * DD + d4 * 4);
        *(uint2*)&E2[e][d4 * 4] = make_uint2(pk2(v.x, v.y), pk2(v.z, v.w));
    }
    __syncthreads();

    const bf16x8* W1v = (const bf16x8*)W1pack;
    const bf16x8* W2v = (const bf16x8*)W2p2;
    int erow[4];
    #pragma unroll
    for (int et = 0; et < 4; ++et) erow[et] = et * 16 + l15;

    f32x4 acc2[4];
    #pragma unroll
    for (int et = 0; et < 4; ++et)
        #pragma unroll
        for (int r = 0; r < 4; ++r) acc2[et][r] = 0.f;

    #pragma unroll
    for (int c = 0; c < 2; ++c) {
        f32x4 acc[4][4];
        // C-in init from per-node pre (broadcast LDS reads; node = et>>1)
        #pragma unroll
        for (int nb = 0; nb < 4; ++nb)
            #pragma unroll
            for (int et = 0; et < 4; ++et)
                acc[nb][et] = *(const f32x4*)&pre_s[(et >> 1) * 576 + wn * 144 + (c * 4 + nb) * 16 + 4 * g];
        // K-loop over h_j/dist only: global ks 4..8
        #pragma unroll
        for (int ks = 0; ks < 5; ++ks) {
            const bf16x8* wp = W1v + ((size_t)((ks + 4) * 36 + wn * 9 + c * 4)) * 64 + lane;
            bf16x8 afr[4];
            #pragma unroll
            for (int nb = 0; nb < 4; ++nb) afr[nb] = wp[nb * 64];
            bf16x8 bfr[4];
            #pragma unroll
            for (int et = 0; et < 4; ++et)
                bfr[et] = *(const bf16x8*)&E2[erow[et]][ks * 32 + 8 * g];
            #pragma unroll
            for (int nb = 0; nb < 4; ++nb)
                #pragma unroll
                for (int et = 0; et < 4; ++et)
                    acc[nb][et] = __builtin_amdgcn_mfma_f32_16x16x32_bf16(afr[nb], bfr[et], acc[nb][et], 0, 0, 0);
        }
        // silu (bias already inside pre)
        #pragma unroll
        for (int nb = 0; nb < 4; ++nb)
            #pragma unroll
            for (int et = 0; et < 4; ++et)
                #pragma unroll
                for (int r = 0; r < 4; ++r)
                    acc[nb][et][r] = silu_f(acc[nb][et][r]);
        // GEMM2: local ks2 = 2c, 2c+1
        #pragma unroll
        for (int qq = 0; qq < 2; ++qq) {
            int ks2 = 2 * c + qq;
            bf16x8 a2 = W2v[(size_t)(wn * 5 + ks2) * 64 + lane];
            #pragma unroll
            for (int et = 0; et < 4; ++et) {
                union { unsigned u[4]; bf16x8 v; } cv;
                cv.u[0] = pk2(acc[2 * qq][et][0], acc[2 * qq][et][1]);
                cv.u[1] = pk2(acc[2 * qq][et][2], acc[2 * qq][et][3]);
                cv.u[2] = pk2(acc[2 * qq + 1][et][0], acc[2 * qq + 1][et][1]);
                cv.u[3] = pk2(acc[2 * qq + 1][et][2], acc[2 * qq + 1][et][3]);
                acc2[et] = __builtin_amdgcn_mfma_f32_16x16x32_bf16(a2, cv.v, acc2[et], 0, 0, 0);
            }
        }
    }
    // tail chunk: nb = 8, ks2 = 4 (upper half zero)
    {
        f32x4 acc8[4];
        #pragma unroll
        for (int et = 0; et < 4; ++et)
            acc8[et] = *(const f32x4*)&pre_s[(et >> 1) * 576 + wn * 144 + 128 + 4 * g];
        #pragma unroll
        for (int ks = 0; ks < 5; ++ks) {
            bf16x8 af = W1v[((size_t)((ks + 4) * 36 + wn * 9 + 8)) * 64 + lane];
            bf16x8 bfr[4];
            #pragma unroll
            for (int et = 0; et < 4; ++et)
                bfr[et] = *(const bf16x8*)&E2[erow[et]][ks * 32 + 8 * g];
            #pragma unroll
            for (int et = 0; et < 4; ++et)
                acc8[et] = __builtin_amdgcn_mfma_f32_16x16x32_bf16(af, bfr[et], acc8[et], 0, 0, 0);
        }
        #pragma unroll
        for (int et = 0; et < 4; ++et)
            #pragma unroll
            for (int r = 0; r < 4; ++r)
                acc8[et][r] = silu_f(acc8[et][r]);
        bf16x8 a2 = W2v[(size_t)(wn * 5 + 4) * 64 + lane];
        #pragma unroll
        for (int et = 0; et < 4; ++et) {
            union { unsigned u[4]; bf16x8 v; } cv;
            cv.u[0] = pk2(acc8[et][0], acc8[et][1]);
            cv.u[1] = pk2(acc8[et][2], acc8[et][3]);
            cv.u[2] = 0; cv.u[3] = 0;
            acc2[et] = __builtin_amdgcn_mfma_f32_16x16x32_bf16(a2, cv.v, acc2[et], 0, 0, 0);
        }
    }
    #pragma unroll
    for (int et = 0; et < 4; ++et)
        *(f32x4*)&m_s4[((wn * 64) + erow[et]) * 16 + 4 * g] = acc2[et];
    __syncthreads();

    #pragma unroll
    for (int i2 = t; i2 < 64 * 16; i2 += 256) {
        int e = i2 >> 4, f = i2 & 15;
        float s = m_s4[e * 16 + f] + m_s4[(64 + e) * 16 + f]
                + m_s4[(128 + e) * 16 + f] + m_s4[(192 + e) * 16 + f];
        m_sF[e * 17 + f] = silu_f(s + be2[f]);
    }
    __syncthreads();

    {
        const int ee = t >> 2, q4 = t & 3;
        const int u0 = q4 * 16;
        float mm[16];
        #pragma unroll
        for (int f = 0; f < 16; ++f) mm[f] = m_sF[ee * 17 + f];
        float h2[16];
        {
            const float4* bp = (const float4*)(bc1 + u0);
            float4 b0 = bp[0], b1 = bp[1], b2v = bp[2], b3 = bp[3];
            h2[0]=b0.x; h2[1]=b0.y; h2[2]=b0.z; h2[3]=b0.w;
            h2[4]=b1.x; h2[5]=b1.y; h2[6]=b1.z; h2[7]=b1.w;
            h2[8]=b2v.x; h2[9]=b2v.y; h2[10]=b2v.z; h2[11]=b2v.w;
            h2[12]=b3.x; h2[13]=b3.y; h2[14]=b3.z; h2[15]=b3.w;
        }
        #pragma unroll
        for (int f = 0; f < 16; ++f) {
            const float4* wp = (const float4*)(Wc1 + (size_t)f * 64 + u0);
            float4 w0 = wp[0], w1 = wp[1], w2 = wp[2], w3 = wp[3];
            float v = mm[f];
            h2[0]  = fmaf(v, w0.x, h2[0]);  h2[1]  = fmaf(v, w0.y, h2[1]);
            h2[2]  = fmaf(v, w0.z, h2[2]);  h2[3]  = fmaf(v, w0.w, h2[3]);
            h2[4]  = fmaf(v, w1.x, h2[4]);  h2[5]  = fmaf(v, w1.y, h2[5]);
            h2[6]  = fmaf(v, w1.z, h2[6]);  h2[7]  = fmaf(v, w1.w, h2[7]);
            h2[8]  = fmaf(v, w2.x, h2[8]);  h2[9]  = fmaf(v, w2.y, h2[9]);
            h2[10] = fmaf(v, w2.z, h2[10]); h2[11] = fmaf(v, w2.w, h2[11]);
            h2[12] = fmaf(v, w3.x, h2[12]); h2[13] = fmaf(v, w3.y, h2[13]);
            h2[14] = fmaf(v, w3.z, h2[14]); h2[15] = fmaf(v, w3.w, h2[15]);
        }
        float cw = 0.f;
        const float4* cp = (const float4*)(Wc2 + u0);
        float4 c0 = cp[0], c1 = cp[1], c2 = cp[2], c3 = cp[3];
        const float wv[16] = {c0.x,c0.y,c0.z,c0.w, c1.x,c1.y,c1.z,c1.w,
                              c2.x,c2.y,c2.z,c2.w, c3.x,c3.y,c3.z,c3.w};
        #pragma unroll
        for (int r = 0; r < 16; ++r) cw = fmaf(silu_f(h2[r]), wv[r], cw);
        cw += __shfl_xor(cw, 1, 64);
        cw += __shfl_xor(cw, 2, 64);
        if (q4 == 0) {
            cw += bc2[0];
            int gnode = gn0 + (ee >> 5);
            int mi = mask[gnode];
            int mj = mask[b * NNODE + j_s[ee]];
            cw_s[ee] = (mi != 0 && mj != 0) ? cw : 0.f;
        }
    }
    __syncthreads();

    if (t < 32) {
        int n = t >> 4, f = t & 15;
        float s = 0.f;
        #pragma unroll
        for (int k2 = 0; k2 < 32; ++k2) s += m_sF[(n * 32 + k2) * 17 + f];
        m_i_out[(size_t)(gn0 + n) * CFX + f] = s;
    } else if (t < 38) {
        int r = t - 32;
        int n = r / 3, c = r - n * 3;
        const float* rp = relk + ((size_t)gn0 * KK + n * 32) * 3 + c;
        float s = 0.f;
        #pragma unroll
        for (int k2 = 0; k2 < 32; ++k2) s = fmaf(cw_s[n * 32 + k2], rp[k2 * 3], s);
        coors_out[(size_t)(gn0 + n) * 3 + c] = s + x[(size_t)(gn0 + n) * 3 + c];
    }
}

// ---------------------------------------------------------------- node MLP via MFMA (R11 exact — proven)
__global__ __launch_bounds__(256) void node_kernel(
    const float* __restrict__ h, const float* __restrict__ m_i,
    const unsigned short* __restrict__ Wn1p, const float* __restrict__ bn1,
    const unsigned short* __restrict__ Wn2p, const float* __restrict__ bn2,
    float* __restrict__ node_out)
{
    __shared__ unsigned short nin[32][168];
    __shared__ unsigned short hid[32][264];

    const int t = threadIdx.x;
    const int gn0 = blockIdx.x * 32;
    const int wn = t >> 6, lane = t & 63;
    const int l15 = lane & 15, g = lane >> 4;

    for (int q = t; q < 32 * 32; q += 256) {
        int node = q >> 5, c4 = q & 31;
        float4 v = *(const float4*)(h + (size_t)(gn0 + node) * DD + c4 * 4);
        *(uint2*)&nin[node][c4 * 4] = make_uint2(pk2(v.x, v.y), pk2(v.z, v.w));
    }
    if (t < 128) {
        int node = t >> 2, c4 = t & 3;
        float4 v = *(const float4*)(m_i + (size_t)(gn0 + node) * CFX + c4 * 4);
        *(uint2*)&nin[node][128 + c4 * 4] = make_uint2(pk2(v.x, v.y), pk2(v.z, v.w));
    } else if (t < 224) {
        int r = t - 128;
        int node = r / 3, cc = (r - node * 3) * 8;
        *(uint4*)&nin[node][144 + cc] = make_uint4(0, 0, 0, 0);
    }
    __syncthreads();

    const bf16x8* A1 = (const bf16x8*)Wn1p;
    f32x4 acc[4][2];
    #pragma unroll
    for (int nb = 0; nb < 4; ++nb)
        #pragma unroll
        for (int et = 0; et < 2; ++et)
            #pragma unroll
            for (int r = 0; r < 4; ++r) acc[nb][et][r] = 0.f;
    #pragma unroll
    for (int ks = 0; ks < 5; ++ks) {
        const bf16x8* wp = A1 + ((size_t)(ks * 16 + wn * 4)) * 64 + lane;
        bf16x8 afr[4];
        #pragma unroll
        for (int nb = 0; nb < 4; ++nb) afr[nb] = wp[nb * 64];
        bf16x8 b0 = *(const bf16x8*)&nin[l15][ks * 32 + 8 * g];
        bf16x8 b1 = *(const bf16x8*)&nin[16 + l15][ks * 32 + 8 * g];
        #pragma unroll
        for (int nb = 0; nb < 4; ++nb) {
            acc[nb][0] = __builtin_amdgcn_mfma_f32_16x16x32_bf16(afr[nb], b0, acc[nb][0], 0, 0, 0);
            acc[nb][1] = __builtin_amdgcn_mfma_f32_16x16x32_bf16(afr[nb], b1, acc[nb][1], 0, 0, 0);
        }
    }
    #pragma unroll
    for (int nb = 0; nb < 4; ++nb) {
        int u0 = (wn * 4 + nb) * 16 + 4 * g;
        f32x4 bv = *(const f32x4*)&bn1[u0];
        #pragma unroll
        for (int et = 0; et < 2; ++et) {
            float s0 = silu_f(acc[nb][et][0] + bv[0]);
            float s1 = silu_f(acc[nb][et][1] + bv[1]);
            float s2 = silu_f(acc[nb][et][2] + bv[2]);
            float s3 = silu_f(acc[nb][et][3] + bv[3]);
            *(uint2*)&hid[et * 16 + l15][u0] = make_uint2(pk2(s0, s1), pk2(s2, s3));
        }
    }
    __syncthreads();

    const bf16x8* A2 = (const bf16x8*)Wn2p;
    f32x4 acc2[2][2];
    #pragma unroll
    for (int nb = 0; nb < 2; ++nb)
        #pragma unroll
        for (int et = 0; et < 2; ++et)
            #pragma unroll
            for (int r = 0; r < 4; ++r) acc2[nb][et][r] = 0.f;
    #pragma unroll
    for (int ks = 0; ks < 8; ++ks) {
        const bf16x8* wp = A2 + ((size_t)(ks * 8 + wn * 2)) * 64 + lane;
        bf16x8 a0 = wp[0], a1 = wp[64];
        bf16x8 b0 = *(const bf16x8*)&hid[l15][ks * 32 + 8 * g];
        bf16x8 b1 = *(const bf16x8*)&hid[16 + l15][ks * 32 + 8 * g];
        acc2[0][0] = __builtin_amdgcn_mfma_f32_16x16x32_bf16(a0, b0, acc2[0][0], 0, 0, 0);
        acc2[0][1] = __builtin_amdgcn_mfma_f32_16x16x32_bf16(a0, b1, acc2[0][1], 0, 0, 0);
        acc2[1][0] = __builtin_amdgcn_mfma_f32_16x16x32_bf16(a1, b0, acc2[1][0], 0, 0, 0);
        acc2[1][1] = __builtin_amdgcn_mfma_f32_16x16x32_bf16(a1, b1, acc2[1][1], 0, 0, 0);
    }
    #pragma unroll
    for (int nb = 0; nb < 2; ++nb) {
        int d0 = (wn * 2 + nb) * 16 + 4 * g;
        f32x4 bv = *(const f32x4*)&bn2[d0];
        #pragma unroll
        for (int et = 0; et < 2; ++et) {
            int gnode = gn0 + et * 16 + l15;
            float4 hv = *(const float4*)(h + (size_t)gnode * DD + d0);
            float4 o;
            o.x = acc2[nb][et][0] + bv[0] + hv.x;
            o.y = acc2[nb][et][1] + bv[1] + hv.y;
            o.z = acc2[nb][et][2] + bv[2] + hv.z;
            o.w = acc2[nb][et][3] + bv[3] + hv.w;
            *(float4*)(node_out + (size_t)gnode * DD + d0) = o;
        }
    }
}

// ---------------------------------------------------------------- launch
extern "C" void kernel_launch(void* const* d_in, const int* in_sizes, int n_in,
                              void* d_out, int out_size, void* d_ws, size_t ws_size,
                              hipStream_t stream) {
    const float* h   = (const float*)d_in[0];
    const float* x   = (const float*)d_in[1];
    const int*   mask= (const int*)d_in[2];
    const float* We1 = (const float*)d_in[3];
    const float* be1 = (const float*)d_in[4];
    const float* We2 = (const float*)d_in[5];
    const float* be2 = (const float*)d_in[6];
    const float* Wc1 = (const float*)d_in[7];
    const float* bc1 = (const float*)d_in[8];
    const float* Wc2 = (const float*)d_in[9];
    const float* bc2 = (const float*)d_in[10];
    const float* Wn1 = (const float*)d_in[11];
    const float* bn1 = (const float*)d_in[12];
    const float* Wn2 = (const float*)d_in[13];
    const float* bn2 = (const float*)d_in[14];

    float* node_out  = (float*)d_out;
    float* coors_out = node_out + (size_t)BB * NNODE * DD;

    char* ws = (char*)d_ws;
    int*   idx    = (int*)ws;            ws += (size_t)BB * NNODE * KK * 4;
    float* relk   = (float*)ws;          ws += (size_t)BB * NNODE * KK * 3 * 4;
    float* distk  = (float*)ws;          ws += (size_t)BB * NNODE * KK * 4;
    float* m_i    = (float*)ws;          ws += (size_t)BB * NNODE * CFX * 4;
    unsigned short* W1pack = (unsigned short*)ws;  ws += (size_t)9 * 36 * 64 * 8 * 2;
    unsigned short* W2p2   = (unsigned short*)ws;  ws += (size_t)4 * 5 * 64 * 8 * 2;
    unsigned short* Wn1p   = (unsigned short*)ws;  ws += (size_t)5 * 16 * 64 * 8 * 2;
    unsigned short* Wn2p   = (unsigned short*)ws;  ws += (size_t)8 * 8 * 64 * 8 * 2;
    float* pre_g  = (float*)ws;          ws += (size_t)BB * NNODE * 576 * 4;   // 18.9 MB

    prep_kernel<<<256, 256, 0, stream>>>(We1, We2, Wn1, Wn2, W1pack, W2p2, Wn1p, Wn2p);
    pre_kernel<<<BB * NNODE / 16, 256, 0, stream>>>(h, be1, W1pack, pre_g);
    knn_kernel<<<BB * NNODE, 256, 0, stream>>>(x, idx, relk, distk);
    edge_kernel<<<BB * NNODE / 2, 256, 0, stream>>>(h, x, mask, be2, Wc1, bc1, Wc2, bc2,
                                                    idx, relk, distk, W1pack, W2p2, pre_g,
                                                    m_i, coors_out);
    node_kernel<<<BB * NNODE / 32, 256, 0, stream>>>(h, m_i, Wn1p, bn1, Wn2p, bn2, node_out);
}

// Round 17
// 275.046 us; speedup vs baseline: 1.3114x; 1.0471x over previous
//
#include <hip/hip_runtime.h>
#include <hip/hip_bf16.h>

// Problem constants (fixed by reference)
#define BB    2
#define NNODE 4096
#define DD    128
#define KK    32
#define CFX   16

typedef __attribute__((ext_vector_type(8))) short bf16x8;
typedef __attribute__((ext_vector_type(4))) float f32x4;

__device__ __forceinline__ unsigned short f2bf(float f) {
    __hip_bfloat16 h = __float2bfloat16(f);
    return *reinterpret_cast<unsigned short*>(&h);
}
__device__ __forceinline__ unsigned pk2(float lo, float hi) {
    __hip_bfloat162 v = __float22bfloat162_rn(make_float2(lo, hi));
    return *reinterpret_cast<unsigned*>(&v);
}
// Fast silu: v * rcp(1+e^-v) — ~1ulp rcp vs full IEEE divide; output bf16-rounded anyway.
__device__ __forceinline__ float silu_f(float v) {
    float e = __expf(-v);
    return v * __builtin_amdgcn_rcpf(1.f + e);
}
// Exact dist (matches reference mul-then-add, no FMA contraction) — bit-identical everywhere.
__device__ __forceinline__ float dist3(float xi0, float xi1, float xi2,
                                       const float* __restrict__ xb, int j) {
    float d0 = __fsub_rn(xi0, xb[3 * j]);
    float d1 = __fsub_rn(xi1, xb[3 * j + 1]);
    float d2 = __fsub_rn(xi2, xb[3 * j + 2]);
    return __fadd_rn(__fadd_rn(__fmul_rn(d0, d0), __fmul_rn(d1, d1)), __fmul_rn(d2, d2));
}

// ---------------------------------------------------------------- prep: pack weights into MFMA fragment layout
__global__ void prep_kernel(const float* __restrict__ We1, const float* __restrict__ We2,
                            const float* __restrict__ Wn1, const float* __restrict__ Wn2,
                            unsigned short* __restrict__ W1pack, unsigned short* __restrict__ W2p2,
                            unsigned short* __restrict__ Wn1p, unsigned short* __restrict__ Wn2p) {
    int tid = blockIdx.x * 256 + threadIdx.x;
    int stride = gridDim.x * 256;
    for (int p = tid; p < 9 * 36 * 64 * 8; p += stride) {
        int i = p & 7, lane = (p >> 3) & 63, rest = p >> 9;
        int nb = rest % 36, ks = rest / 36;
        int n = nb * 16 + (lane & 15);
        int k = ks * 32 + 8 * (lane >> 4) + i;
        W1pack[p] = (k < 257 && n < 514) ? f2bf(We1[k * 514 + n]) : (unsigned short)0;
    }
    for (int p = tid; p < 4 * 5 * 64 * 8; p += stride) {
        int i = p & 7, lane = (p >> 3) & 63, rest = p >> 9;
        int ks2 = rest % 5, wn = rest / 5;
        int g = lane >> 4, f = lane & 15;
        int nloc = ks2 * 32 + 16 * (i >> 2) + 4 * g + (i & 3);
        int ng = wn * 144 + nloc;
        W2p2[p] = (nloc < 144 && ng < 514) ? f2bf(We2[ng * 16 + f]) : (unsigned short)0;
    }
    for (int p = tid; p < 5 * 16 * 64 * 8; p += stride) {
        int i = p & 7, lane = (p >> 3) & 63, rest = p >> 9;
        int nb = rest % 16, ks = rest / 16;
        int u = nb * 16 + (lane & 15);
        int k = ks * 32 + 8 * (lane >> 4) + i;
        Wn1p[p] = (k < 144) ? f2bf(Wn1[k * 256 + u]) : (unsigned short)0;
    }
    for (int p = tid; p < 8 * 8 * 64 * 8; p += stride) {
        int i = p & 7, lane = (p >> 3) & 63, rest = p >> 9;
        int nb = rest % 8, ks = rest / 8;
        int d = nb * 16 + (lane & 15);
        int k = ks * 32 + 8 * (lane >> 4) + i;
        Wn2p[p] = f2bf(Wn2[k * 128 + d]);
    }
}

// ---------------------------------------------------------------- pre: BOTH per-node halves of edge GEMM1
// preI[node][n] = sum_{k<128}     We1[k][n]    *bf16(h[k]) + be1[n]   (f32)
// preJ[node][n] = sum_{k<128}     We1[128+k][n]*bf16(h[k])            (bf16)
// Block = 16 nodes, 256 threads; wave wn owns a 144-wide n-slice.
__global__ __launch_bounds__(256) void pre_kernel(
    const float* __restrict__ h, const float* __restrict__ be1,
    const unsigned short* __restrict__ W1pack,
    float* __restrict__ preI_g, unsigned short* __restrict__ preJ_g)
{
    __shared__ unsigned short nin[16][136];
    const int t = threadIdx.x;
    const int gn0 = blockIdx.x * 16;
    const int wn = t >> 6, lane = t & 63;
    const int l15 = lane & 15, g = lane >> 4;

    for (int q = t; q < 16 * 32; q += 256) {
        int node = q >> 5, c4 = q & 31;
        float4 v = *(const float4*)(h + (size_t)(gn0 + node) * DD + c4 * 4);
        *(uint2*)&nin[node][c4 * 4] = make_uint2(pk2(v.x, v.y), pk2(v.z, v.w));
    }
    __syncthreads();

    const bf16x8* W1v = (const bf16x8*)W1pack;
    // ---- preI: weight ks 0..3
    {
        f32x4 acc[9];
        #pragma unroll
        for (int nb = 0; nb < 9; ++nb)
            #pragma unroll
            for (int r = 0; r < 4; ++r) acc[nb][r] = 0.f;
        #pragma unroll
        for (int ks = 0; ks < 4; ++ks) {
            bf16x8 bfr = *(const bf16x8*)&nin[l15][ks * 32 + 8 * g];
            #pragma unroll
            for (int nb = 0; nb < 9; ++nb) {
                bf16x8 af = W1v[((size_t)(ks * 36 + wn * 9 + nb)) * 64 + lane];
                acc[nb] = __builtin_amdgcn_mfma_f32_16x16x32_bf16(af, bfr, acc[nb], 0, 0, 0);
            }
        }
        float* outp = preI_g + (size_t)(gn0 + l15) * 576;
        #pragma unroll
        for (int nb = 0; nb < 9; ++nb) {
            int n0 = wn * 144 + nb * 16 + 4 * g;
            float4 o;
            o.x = acc[nb][0] + ((n0 + 0) < 514 ? be1[n0 + 0] : 0.f);
            o.y = acc[nb][1] + ((n0 + 1) < 514 ? be1[n0 + 1] : 0.f);
            o.z = acc[nb][2] + ((n0 + 2) < 514 ? be1[n0 + 2] : 0.f);
            o.w = acc[nb][3] + ((n0 + 3) < 514 ? be1[n0 + 3] : 0.f);
            *(float4*)(outp + n0) = o;
        }
    }
    // ---- preJ: weight ks 4..7 (same B fragments), bf16 output, no bias
    {
        f32x4 acc[9];
        #pragma unroll
        for (int nb = 0; nb < 9; ++nb)
            #pragma unroll
            for (int r = 0; r < 4; ++r) acc[nb][r] = 0.f;
        #pragma unroll
        for (int ks = 0; ks < 4; ++ks) {
            bf16x8 bfr = *(const bf16x8*)&nin[l15][ks * 32 + 8 * g];
            #pragma unroll
            for (int nb = 0; nb < 9; ++nb) {
                bf16x8 af = W1v[((size_t)((ks + 4) * 36 + wn * 9 + nb)) * 64 + lane];
                acc[nb] = __builtin_amdgcn_mfma_f32_16x16x32_bf16(af, bfr, acc[nb], 0, 0, 0);
            }
        }
        unsigned short* outp = preJ_g + (size_t)(gn0 + l15) * 576;
        #pragma unroll
        for (int nb = 0; nb < 9; ++nb) {
            int n0 = wn * 144 + nb * 16 + 4 * g;
            *(uint2*)(outp + n0) = make_uint2(pk2(acc[nb][0], acc[nb][1]), pk2(acc[nb][2], acc[nb][3]));
        }
    }
}

// ---------------------------------------------------------------- kNN v4 (R13 exact — proven)
#define EQCAP 36
#define CANDCAP 1024
__global__ __launch_bounds__(256) void knn_kernel(const float* __restrict__ x,
                                                  int* __restrict__ idx_o,
                                                  float* __restrict__ relk_o,
                                                  float* __restrict__ distk_o) {
    __shared__ unsigned hist[4][256];
    __shared__ unsigned wsum[4];
    __shared__ unsigned sel[2];
    __shared__ unsigned shA, shB;
    __shared__ int out_j[KK];
    __shared__ int eqbuf[EQCAP];
    __shared__ uint2 cand[CANDCAP];

    const int t = threadIdx.x;
    const int ln = t & 63, wv = t >> 6;
    const int gn = blockIdx.x;
    const int b = gn >> 12, i = gn & 4095;
    const float* xb = x + (size_t)b * NNODE * 3;
    const float xi0 = xb[3 * i], xi1 = xb[3 * i + 1], xi2 = xb[3 * i + 2];

    #pragma unroll
    for (int q2 = 0; q2 < 4; ++q2) hist[q2][t] = 0;
    __syncthreads();

    unsigned ub[16];
    #pragma unroll
    for (int s = 0; s < 16; ++s) {
        float d = dist3(xi0, xi1, xi2, xb, t + 256 * s);
        ub[s] = __float_as_uint(d);
        atomicAdd(&hist[wv][ub[s] >> 24], 1u);
    }
    __syncthreads();

    int kk = KK;
    {
        unsigned hv = hist[0][t] + hist[1][t] + hist[2][t] + hist[3][t];
        unsigned v = hv;
        #pragma unroll
        for (int off = 1; off < 64; off <<= 1) {
            unsigned o = __shfl_up(v, off, 64);
            if (ln >= off) v += o;
        }
        if (ln == 63) wsum[wv] = v;
        __syncthreads();
        unsigned add = 0;
        #pragma unroll
        for (int w = 0; w < 4; ++w) add += (w < wv) ? wsum[w] : 0u;
        unsigned incl = v + add, excl = incl - hv;
        if ((unsigned)kk > excl && (unsigned)kk <= incl) { sel[0] = (unsigned)t; sel[1] = (unsigned)kk - excl; }
        __syncthreads();
    }
    unsigned prefix = sel[0];
    kk = (int)sel[1];
    __syncthreads();

    unsigned pc = 0;
    #pragma unroll
    for (int s = 0; s < 16; ++s) {
        unsigned tb = ub[s] >> 24;
        pc += (tb < prefix) ? 0x10000u : (tb == prefix ? 1u : 0u);
    }
    {
        unsigned v = pc;
        #pragma unroll
        for (int off = 1; off < 64; off <<= 1) {
            unsigned o = __shfl_up(v, off, 64);
            if (ln >= off) v += o;
        }
        if (ln == 63) wsum[wv] = v;
        __syncthreads();
        unsigned add = 0;
        #pragma unroll
        for (int w = 0; w < 4; ++w) add += (w < wv) ? wsum[w] : 0u;
        unsigned incl = v + add, excl = incl - pc;
        if (t == 255) { shA = incl >> 16; shB = incl & 0xFFFFu; }
        __syncthreads();
        unsigned wl = excl >> 16, wc = excl & 0xFFFFu;
        #pragma unroll
        for (int s = 0; s < 16; ++s) {
            unsigned u = ub[s];
            unsigned tb = u >> 24;
            int j = t + 256 * s;
            if (tb < prefix) { out_j[wl++] = j; }
            else if (tb == prefix) { if (wc < CANDCAP) cand[wc] = make_uint2(u, (unsigned)j); ++wc; }
        }
    }
    __syncthreads();
    const unsigned totL0 = shA, totC = shB;
    const bool fullscan = (totC > CANDCAP);

    for (int r = 1; r < 4; ++r) {
        const int sh = 24 - 8 * r;
        #pragma unroll
        for (int q2 = 0; q2 < 4; ++q2) hist[q2][t] = 0;
        __syncthreads();
        if (!fullscan) {
            for (int ii = t; ii < (int)totC; ii += 256) {
                unsigned u = cand[ii].x;
                if ((u >> (sh + 8)) == prefix) atomicAdd(&hist[wv][(u >> sh) & 255], 1u);
            }
        } else {
            #pragma unroll
            for (int s = 0; s < 16; ++s) {
                unsigned u = ub[s];
                if ((u >> (sh + 8)) == prefix) atomicAdd(&hist[wv][(u >> sh) & 255], 1u);
            }
        }
        __syncthreads();
        unsigned hv = hist[0][t] + hist[1][t] + hist[2][t] + hist[3][t];
        unsigned v = hv;
        #pragma unroll
        for (int off = 1; off < 64; off <<= 1) {
            unsigned o = __shfl_up(v, off, 64);
            if (ln >= off) v += o;
        }
        if (ln == 63) wsum[wv] = v;
        __syncthreads();
        unsigned add = 0;
        #pragma unroll
        for (int w = 0; w < 4; ++w) add += (w < wv) ? wsum[w] : 0u;
        unsigned incl = v + add, excl = incl - hv;
        if ((unsigned)kk > excl && (unsigned)kk <= incl) { sel[0] = (unsigned)t; sel[1] = (unsigned)kk - excl; }
        __syncthreads();
        prefix = (prefix << 8) | sel[0];
        kk = (int)sel[1];
        __syncthreads();
    }
    const unsigned T = prefix;

    int totL;
    if (!fullscan) {
        unsigned pc2 = 0;
        for (int ii = t; ii < (int)totC; ii += 256) {
            unsigned u = cand[ii].x;
            pc2 += (u < T) ? 0x10000u : (u == T ? 1u : 0u);
        }
        unsigned v = pc2;
        #pragma unroll
        for (int off = 1; off < 64; off <<= 1) {
            unsigned o = __shfl_up(v, off, 64);
            if (ln >= off) v += o;
        }
        if (ln == 63) wsum[wv] = v;
        __syncthreads();
        unsigned add = 0;
        #pragma unroll
        for (int w = 0; w < 4; ++w) add += (w < wv) ? wsum[w] : 0u;
        unsigned incl = v + add, excl = incl - pc2;
        if (t == 255) { shA = incl >> 16; shB = incl & 0xFFFFu; }
        __syncthreads();
        unsigned w2 = totL0 + (excl >> 16), we = excl & 0xFFFFu;
        for (int ii = t; ii < (int)totC; ii += 256) {
            unsigned u = cand[ii].x;
            int j = (int)cand[ii].y;
            if (u < T) { out_j[w2++] = j; }
            else if (u == T) { if (we < EQCAP) eqbuf[we] = j; ++we; }
        }
        __syncthreads();
        totL = (int)(totL0 + shA);
        const unsigned totE = shB;
        if (t == 0) {
            int need = KK - totL;
            if (totE <= EQCAP) {
                for (int a = 1; a < (int)totE; ++a) {
                    int key = eqbuf[a], c = a - 1;
                    while (c >= 0 && eqbuf[c] > key) { eqbuf[c + 1] = eqbuf[c]; --c; }
                    eqbuf[c + 1] = key;
                }
                for (int q = 0; q < need; ++q) out_j[totL + q] = eqbuf[q];
            } else {
                int taken = 0;
                for (int j = 0; j < NNODE && taken < need; ++j)
                    if (__float_as_uint(dist3(xi0, xi1, xi2, xb, j)) == T) out_j[totL + taken++] = j;
            }
        }
    } else {
        unsigned pc2 = 0;
        #pragma unroll
        for (int s = 0; s < 16; ++s) {
            unsigned u = ub[s];
            pc2 += (u < T) ? 0x10000u : (u == T ? 1u : 0u);
        }
        unsigned v = pc2;
        #pragma unroll
        for (int off = 1; off < 64; off <<= 1) {
            unsigned o = __shfl_up(v, off, 64);
            if (ln >= off) v += o;
        }
        if (ln == 63) wsum[wv] = v;
        __syncthreads();
        unsigned add = 0;
        #pragma unroll
        for (int w = 0; w < 4; ++w) add += (w < wv) ? wsum[w] : 0u;
        unsigned incl = v + add, excl = incl - pc2;
        if (t == 255) { shA = incl >> 16; shB = incl & 0xFFFFu; }
        __syncthreads();
        unsigned w2 = excl >> 16, we = excl & 0xFFFFu;
        #pragma unroll
        for (int s = 0; s < 16; ++s) {
            unsigned u = ub[s];
            int j = t + 256 * s;
            if (u < T) { out_j[w2++] = j; }
            else if (u == T) { if (we < EQCAP) eqbuf[we] = j; ++we; }
        }
        __syncthreads();
        totL = (int)shA;
        const unsigned totE = shB;
        if (t == 0) {
            int need = KK - totL;
            if (totE <= EQCAP) {
                for (int a = 1; a < (int)totE; ++a) {
                    int key = eqbuf[a], c = a - 1;
                    while (c >= 0 && eqbuf[c] > key) { eqbuf[c + 1] = eqbuf[c]; --c; }
                    eqbuf[c + 1] = key;
                }
                for (int q = 0; q < need; ++q) out_j[totL + q] = eqbuf[q];
            } else {
                int taken = 0;
                for (int j = 0; j < NNODE && taken < need; ++j)
                    if (__float_as_uint(dist3(xi0, xi1, xi2, xb, j)) == T) out_j[totL + taken++] = j;
            }
        }
    }
    __syncthreads();

    if (t < KK) {
        int j = out_j[t];
        size_t eo = (size_t)gn * KK + t;
        idx_o[eo] = j;
        float r0 = __fsub_rn(xi0, xb[3 * j]);
        float r1 = __fsub_rn(xi1, xb[3 * j + 1]);
        float r2 = __fsub_rn(xi2, xb[3 * j + 2]);
        relk_o[eo * 3 + 0] = r0;
        relk_o[eo * 3 + 1] = r1;
        relk_o[eo * 3 + 2] = r2;
        distk_o[eo] = __fadd_rn(__fadd_rn(__fmul_rn(r0, r0), __fmul_rn(r1, r1)), __fmul_rn(r2, r2));
    }
}

// ---------------------------------------------------------------- edge: GEMM1 fully factored out
// m1[e][n] = preI[i][n] + preJ[j][n] + dist_e*wd[n] — assembled by VALU straight into the
// GEMM2 B-fragment slots (no MFMA, no E2/h_j staging, no K-loop). GEMM2 + epilogue = R16
// exact. Default launch_bounds (no cap): smaller live set may reach 3 waves/SIMD naturally.
__global__ __launch_bounds__(256) void edge_kernel(
    const float* __restrict__ x, const int* __restrict__ mask,
    const float* __restrict__ We1, const float* __restrict__ be2,
    const float* __restrict__ Wc1, const float* __restrict__ bc1,
    const float* __restrict__ Wc2, const float* __restrict__ bc2,
    const int* __restrict__ idx, const float* __restrict__ relk, const float* __restrict__ distk,
    const unsigned short* __restrict__ W2p2,
    const float* __restrict__ preI_g, const unsigned short* __restrict__ preJ_g,
    float* __restrict__ m_i_out, float* __restrict__ coors_out)
{
    __shared__ float pre_s[2 * 576];
    __shared__ float wd_s[576];
    __shared__ int   j_s[64];
    __shared__ float dist_s[64];
    __shared__ float cw_s[64];
    __shared__ float m_s4[4 * 64 * 16];
    __shared__ float m_sF[64 * 17];

    const int t = threadIdx.x;
    const int gn0 = blockIdx.x * 2;
    const int b = gn0 >> 12;
    const int wn = t >> 6, lane = t & 63;
    const int l15 = lane & 15, g = lane >> 4;

    if (t < 64) {
        size_t eo = (size_t)gn0 * KK + t;
        j_s[t] = idx[eo];
        dist_s[t] = distk[eo];
    }
    for (int i2 = t; i2 < 576; i2 += 256) wd_s[i2] = (i2 < 514) ? We1[256 * 514 + i2] : 0.f;
    {
        const float4* src = (const float4*)(preI_g + (size_t)gn0 * 576);
        float4* dst = (float4*)pre_s;
        for (int i2 = t; i2 < 288; i2 += 256) dst[i2] = src[i2];
    }
    __syncthreads();

    const bf16x8* W2v = (const bf16x8*)W2p2;
    int erow[4];
    size_t jrow[4];
    float de[4];
    #pragma unroll
    for (int et = 0; et < 4; ++et) {
        erow[et] = et * 16 + l15;
        jrow[et] = ((size_t)b * NNODE + j_s[erow[et]]) * 576;
        de[et] = dist_s[erow[et]];
    }

    f32x4 acc2[4];
    #pragma unroll
    for (int et = 0; et < 4; ++et)
        #pragma unroll
        for (int r = 0; r < 4; ++r) acc2[et][r] = 0.f;

    #pragma unroll
    for (int c = 0; c < 2; ++c) {
        f32x4 acc[4][4];
        #pragma unroll
        for (int nb = 0; nb < 4; ++nb) {
            const int n0 = wn * 144 + (c * 4 + nb) * 16 + 4 * g;
            f32x4 wdv = *(const f32x4*)&wd_s[n0];
            #pragma unroll
            for (int et = 0; et < 4; ++et) {
                f32x4 pi = *(const f32x4*)&pre_s[(et >> 1) * 576 + n0];
                uint2 pj = *(const uint2*)(preJ_g + jrow[et] + n0);
                float p0 = __uint_as_float(pj.x << 16);
                float p1 = __uint_as_float(pj.x & 0xFFFF0000u);
                float p2 = __uint_as_float(pj.y << 16);
                float p3 = __uint_as_float(pj.y & 0xFFFF0000u);
                acc[nb][et][0] = silu_f(pi[0] + p0 + de[et] * wdv[0]);
                acc[nb][et][1] = silu_f(pi[1] + p1 + de[et] * wdv[1]);
                acc[nb][et][2] = silu_f(pi[2] + p2 + de[et] * wdv[2]);
                acc[nb][et][3] = silu_f(pi[3] + p3 + de[et] * wdv[3]);
            }
        }
        // GEMM2: local ks2 = 2c, 2c+1 (unchanged)
        #pragma unroll
        for (int qq = 0; qq < 2; ++qq) {
            int ks2 = 2 * c + qq;
            bf16x8 a2 = W2v[(size_t)(wn * 5 + ks2) * 64 + lane];
            #pragma unroll
            for (int et = 0; et < 4; ++et) {
                union { unsigned u[4]; bf16x8 v; } cv;
                cv.u[0] = pk2(acc[2 * qq][et][0], acc[2 * qq][et][1]);
                cv.u[1] = pk2(acc[2 * qq][et][2], acc[2 * qq][et][3]);
                cv.u[2] = pk2(acc[2 * qq + 1][et][0], acc[2 * qq + 1][et][1]);
                cv.u[3] = pk2(acc[2 * qq + 1][et][2], acc[2 * qq + 1][et][3]);
                acc2[et] = __builtin_amdgcn_mfma_f32_16x16x32_bf16(a2, cv.v, acc2[et], 0, 0, 0);
            }
        }
    }
    // tail: nb = 8, ks2 = 4 (upper half zero)
    {
        f32x4 acc8[4];
        const int n0 = wn * 144 + 128 + 4 * g;
        f32x4 wdv = *(const f32x4*)&wd_s[n0];
        #pragma unroll
        for (int et = 0; et < 4; ++et) {
            f32x4 pi = *(const f32x4*)&pre_s[(et >> 1) * 576 + n0];
            uint2 pj = *(const uint2*)(preJ_g + jrow[et] + n0);
            float p0 = __uint_as_float(pj.x << 16);
            float p1 = __uint_as_float(pj.x & 0xFFFF0000u);
            float p2 = __uint_as_float(pj.y << 16);
            float p3 = __uint_as_float(pj.y & 0xFFFF0000u);
            acc8[et][0] = silu_f(pi[0] + p0 + de[et] * wdv[0]);
            acc8[et][1] = silu_f(pi[1] + p1 + de[et] * wdv[1]);
            acc8[et][2] = silu_f(pi[2] + p2 + de[et] * wdv[2]);
            acc8[et][3] = silu_f(pi[3] + p3 + de[et] * wdv[3]);
        }
        bf16x8 a2 = W2v[(size_t)(wn * 5 + 4) * 64 + lane];
        #pragma unroll
        for (int et = 0; et < 4; ++et) {
            union { unsigned u[4]; bf16x8 v; } cv;
            cv.u[0] = pk2(acc8[et][0], acc8[et][1]);
            cv.u[1] = pk2(acc8[et][2], acc8[et][3]);
            cv.u[2] = 0; cv.u[3] = 0;
            acc2[et] = __builtin_amdgcn_mfma_f32_16x16x32_bf16(a2, cv.v, acc2[et], 0, 0, 0);
        }
    }
    #pragma unroll
    for (int et = 0; et < 4; ++et)
        *(f32x4*)&m_s4[((wn * 64) + erow[et]) * 16 + 4 * g] = acc2[et];
    __syncthreads();

    #pragma unroll
    for (int i2 = t; i2 < 64 * 16; i2 += 256) {
        int e = i2 >> 4, f = i2 & 15;
        float s = m_s4[e * 16 + f] + m_s4[(64 + e) * 16 + f]
                + m_s4[(128 + e) * 16 + f] + m_s4[(192 + e) * 16 + f];
        m_sF[e * 17 + f] = silu_f(s + be2[f]);
    }
    __syncthreads();

    {
        const int ee = t >> 2, q4 = t & 3;
        const int u0 = q4 * 16;
        float mm[16];
        #pragma unroll
        for (int f = 0; f < 16; ++f) mm[f] = m_sF[ee * 17 + f];
        float h2[16];
        {
            const float4* bp = (const float4*)(bc1 + u0);
            float4 b0 = bp[0], b1 = bp[1], b2v = bp[2], b3 = bp[3];
            h2[0]=b0.x; h2[1]=b0.y; h2[2]=b0.z; h2[3]=b0.w;
            h2[4]=b1.x; h2[5]=b1.y; h2[6]=b1.z; h2[7]=b1.w;
            h2[8]=b2v.x; h2[9]=b2v.y; h2[10]=b2v.z; h2[11]=b2v.w;
            h2[12]=b3.x; h2[13]=b3.y; h2[14]=b3.z; h2[15]=b3.w;
        }
        #pragma unroll
        for (int f = 0; f < 16; ++f) {
            const float4* wp = (const float4*)(Wc1 + (size_t)f * 64 + u0);
            float4 w0 = wp[0], w1 = wp[1], w2 = wp[2], w3 = wp[3];
            float v = mm[f];
            h2[0]  = fmaf(v, w0.x, h2[0]);  h2[1]  = fmaf(v, w0.y, h2[1]);
            h2[2]  = fmaf(v, w0.z, h2[2]);  h2[3]  = fmaf(v, w0.w, h2[3]);
            h2[4]  = fmaf(v, w1.x, h2[4]);  h2[5]  = fmaf(v, w1.y, h2[5]);
            h2[6]  = fmaf(v, w1.z, h2[6]);  h2[7]  = fmaf(v, w1.w, h2[7]);
            h2[8]  = fmaf(v, w2.x, h2[8]);  h2[9]  = fmaf(v, w2.y, h2[9]);
            h2[10] = fmaf(v, w2.z, h2[10]); h2[11] = fmaf(v, w2.w, h2[11]);
            h2[12] = fmaf(v, w3.x, h2[12]); h2[13] = fmaf(v, w3.y, h2[13]);
            h2[14] = fmaf(v, w3.z, h2[14]); h2[15] = fmaf(v, w3.w, h2[15]);
        }
        float cw = 0.f;
        const float4* cp = (const float4*)(Wc2 + u0);
        float4 c0 = cp[0], c1 = cp[1], c2 = cp[2], c3 = cp[3];
        const float wv[16] = {c0.x,c0.y,c0.z,c0.w, c1.x,c1.y,c1.z,c1.w,
                              c2.x,c2.y,c2.z,c2.w, c3.x,c3.y,c3.z,c3.w};
        #pragma unroll
        for (int r = 0; r < 16; ++r) cw = fmaf(silu_f(h2[r]), wv[r], cw);
        cw += __shfl_xor(cw, 1, 64);
        cw += __shfl_xor(cw, 2, 64);
        if (q4 == 0) {
            cw += bc2[0];
            int gnode = gn0 + (ee >> 5);
            int mi = mask[gnode];
            int mj = mask[b * NNODE + j_s[ee]];
            cw_s[ee] = (mi != 0 && mj != 0) ? cw : 0.f;
        }
    }
    __syncthreads();

    if (t < 32) {
        int n = t >> 4, f = t & 15;
        float s = 0.f;
        #pragma unroll
        for (int k2 = 0; k2 < 32; ++k2) s += m_sF[(n * 32 + k2) * 17 + f];
        m_i_out[(size_t)(gn0 + n) * CFX + f] = s;
    } else if (t < 38) {
        int r = t - 32;
        int n = r / 3, c = r - n * 3;
        const float* rp = relk + ((size_t)gn0 * KK + n * 32) * 3 + c;
        float s = 0.f;
        #pragma unroll
        for (int k2 = 0; k2 < 32; ++k2) s = fmaf(cw_s[n * 32 + k2], rp[k2 * 3], s);
        coors_out[(size_t)(gn0 + n) * 3 + c] = s + x[(size_t)(gn0 + n) * 3 + c];
    }
}

// ---------------------------------------------------------------- node MLP via MFMA (R11 exact — proven)
__global__ __launch_bounds__(256) void node_kernel(
    const float* __restrict__ h, const float* __restrict__ m_i,
    const unsigned short* __restrict__ Wn1p, const float* __restrict__ bn1,
    const unsigned short* __restrict__ Wn2p, const float* __restrict__ bn2,
    float* __restrict__ node_out)
{
    __shared__ unsigned short nin[32][168];
    __shared__ unsigned short hid[32][264];

    const int t = threadIdx.x;
    const int gn0 = blockIdx.x * 32;
    const int wn = t >> 6, lane = t & 63;
    const int l15 = lane & 15, g = lane >> 4;

    for (int q = t; q < 32 * 32; q += 256) {
        int node = q >> 5, c4 = q & 31;
        float4 v = *(const float4*)(h + (size_t)(gn0 + node) * DD + c4 * 4);
        *(uint2*)&nin[node][c4 * 4] = make_uint2(pk2(v.x, v.y), pk2(v.z, v.w));
    }
    if (t < 128) {
        int node = t >> 2, c4 = t & 3;
        float4 v = *(const float4*)(m_i + (size_t)(gn0 + node) * CFX + c4 * 4);
        *(uint2*)&nin[node][128 + c4 * 4] = make_uint2(pk2(v.x, v.y), pk2(v.z, v.w));
    } else if (t < 224) {
        int r = t - 128;
        int node = r / 3, cc = (r - node * 3) * 8;
        *(uint4*)&nin[node][144 + cc] = make_uint4(0, 0, 0, 0);
    }
    __syncthreads();

    const bf16x8* A1 = (const bf16x8*)Wn1p;
    f32x4 acc[4][2];
    #pragma unroll
    for (int nb = 0; nb < 4; ++nb)
        #pragma unroll
        for (int et = 0; et < 2; ++et)
            #pragma unroll
            for (int r = 0; r < 4; ++r) acc[nb][et][r] = 0.f;
    #pragma unroll
    for (int ks = 0; ks < 5; ++ks) {
        const bf16x8* wp = A1 + ((size_t)(ks * 16 + wn * 4)) * 64 + lane;
        bf16x8 afr[4];
        #pragma unroll
        for (int nb = 0; nb < 4; ++nb) afr[nb] = wp[nb * 64];
        bf16x8 b0 = *(const bf16x8*)&nin[l15][ks * 32 + 8 * g];
        bf16x8 b1 = *(const bf16x8*)&nin[16 + l15][ks * 32 + 8 * g];
        #pragma unroll
        for (int nb = 0; nb < 4; ++nb) {
            acc[nb][0] = __builtin_amdgcn_mfma_f32_16x16x32_bf16(afr[nb], b0, acc[nb][0], 0, 0, 0);
            acc[nb][1] = __builtin_amdgcn_mfma_f32_16x16x32_bf16(afr[nb], b1, acc[nb][1], 0, 0, 0);
        }
    }
    #pragma unroll
    for (int nb = 0; nb < 4; ++nb) {
        int u0 = (wn * 4 + nb) * 16 + 4 * g;
        f32x4 bv = *(const f32x4*)&bn1[u0];
        #pragma unroll
        for (int et = 0; et < 2; ++et) {
            float s0 = silu_f(acc[nb][et][0] + bv[0]);
            float s1 = silu_f(acc[nb][et][1] + bv[1]);
            float s2 = silu_f(acc[nb][et][2] + bv[2]);
            float s3 = silu_f(acc[nb][et][3] + bv[3]);
            *(uint2*)&hid[et * 16 + l15][u0] = make_uint2(pk2(s0, s1), pk2(s2, s3));
        }
    }
    __syncthreads();

    const bf16x8* A2 = (const bf16x8*)Wn2p;
    f32x4 acc2[2][2];
    #pragma unroll
    for (int nb = 0; nb < 2; ++nb)
        #pragma unroll
        for (int et = 0; et < 2; ++et)
            #pragma unroll
            for (int r = 0; r < 4; ++r) acc2[nb][et][r] = 0.f;
    #pragma unroll
    for (int ks = 0; ks < 8; ++ks) {
        const bf16x8* wp = A2 + ((size_t)(ks * 8 + wn * 2)) * 64 + lane;
        bf16x8 a0 = wp[0], a1 = wp[64];
        bf16x8 b0 = *(const bf16x8*)&hid[l15][ks * 32 + 8 * g];
        bf16x8 b1 = *(const bf16x8*)&hid[16 + l15][ks * 32 + 8 * g];
        acc2[0][0] = __builtin_amdgcn_mfma_f32_16x16x32_bf16(a0, b0, acc2[0][0], 0, 0, 0);
        acc2[0][1] = __builtin_amdgcn_mfma_f32_16x16x32_bf16(a0, b1, acc2[0][1], 0, 0, 0);
        acc2[1][0] = __builtin_amdgcn_mfma_f32_16x16x32_bf16(a1, b0, acc2[1][0], 0, 0, 0);
        acc2[1][1] = __builtin_amdgcn_mfma_f32_16x16x32_bf16(a1, b1, acc2[1][1], 0, 0, 0);
    }
    #pragma unroll
    for (int nb = 0; nb < 2; ++nb) {
        int d0 = (wn * 2 + nb) * 16 + 4 * g;
        f32x4 bv = *(const f32x4*)&bn2[d0];
        #pragma unroll
        for (int et = 0; et < 2; ++et) {
            int gnode = gn0 + et * 16 + l15;
            float4 hv = *(const float4*)(h + (size_t)gnode * DD + d0);
            float4 o;
            o.x = acc2[nb][et][0] + bv[0] + hv.x;
            o.y = acc2[nb][et][1] + bv[1] + hv.y;
            o.z = acc2[nb][et][2] + bv[2] + hv.z;
            o.w = acc2[nb][et][3] + bv[3] + hv.w;
            *(float4*)(node_out + (size_t)gnode * DD + d0) = o;
        }
    }
}

// ---------------------------------------------------------------- launch
extern "C" void kernel_launch(void* const* d_in, const int* in_sizes, int n_in,
                              void* d_out, int out_size, void* d_ws, size_t ws_size,
                              hipStream_t stream) {
    const float* h   = (const float*)d_in[0];
    const float* x   = (const float*)d_in[1];
    const int*   mask= (const int*)d_in[2];
    const float* We1 = (const float*)d_in[3];
    const float* be1 = (const float*)d_in[4];
    const float* We2 = (const float*)d_in[5];
    const float* be2 = (const float*)d_in[6];
    const float* Wc1 = (const float*)d_in[7];
    const float* bc1 = (const float*)d_in[8];
    const float* Wc2 = (const float*)d_in[9];
    const float* bc2 = (const float*)d_in[10];
    const float* Wn1 = (const float*)d_in[11];
    const float* bn1 = (const float*)d_in[12];
    const float* Wn2 = (const float*)d_in[13];
    const float* bn2 = (const float*)d_in[14];

    float* node_out  = (float*)d_out;
    float* coors_out = node_out + (size_t)BB * NNODE * DD;

    char* ws = (char*)d_ws;
    int*   idx    = (int*)ws;            ws += (size_t)BB * NNODE * KK * 4;
    float* relk   = (float*)ws;          ws += (size_t)BB * NNODE * KK * 3 * 4;
    float* distk  = (float*)ws;          ws += (size_t)BB * NNODE * KK * 4;
    float* m_i    = (float*)ws;          ws += (size_t)BB * NNODE * CFX * 4;
    unsigned short* W1pack = (unsigned short*)ws;  ws += (size_t)9 * 36 * 64 * 8 * 2;
    unsigned short* W2p2   = (unsigned short*)ws;  ws += (size_t)4 * 5 * 64 * 8 * 2;
    unsigned short* Wn1p   = (unsigned short*)ws;  ws += (size_t)5 * 16 * 64 * 8 * 2;
    unsigned short* Wn2p   = (unsigned short*)ws;  ws += (size_t)8 * 8 * 64 * 8 * 2;
    float* preI_g = (float*)ws;          ws += (size_t)BB * NNODE * 576 * 4;   // 18.9 MB
    unsigned short* preJ_g = (unsigned short*)ws;  ws += (size_t)BB * NNODE * 576 * 2;  // 9.4 MB

    prep_kernel<<<256, 256, 0, stream>>>(We1, We2, Wn1, Wn2, W1pack, W2p2, Wn1p, Wn2p);
    pre_kernel<<<BB * NNODE / 16, 256, 0, stream>>>(h, be1, W1pack, preI_g, preJ_g);
    knn_kernel<<<BB * NNODE, 256, 0, stream>>>(x, idx, relk, distk);
    edge_kernel<<<BB * NNODE / 2, 256, 0, stream>>>(x, mask, We1, be2, Wc1, bc1, Wc2, bc2,
                                                    idx, relk, distk, W2p2, preI_g, preJ_g,
                                                    m_i, coors_out);
    node_kernel<<<BB * NNODE / 32, 256, 0, stream>>>(h, m_i, Wn1p, bn1, Wn2p, bn2, node_out);
}